// Round 3
// baseline (3013.487 us; speedup 1.0000x reference)
//
#include <hip/hip_runtime.h>

#define NN 100000
#define NE 1600000
#define BN_EPS 1e-5f
#define NFINE 782   // ceil(NN/128)
#define NCOARSE 98  // ceil(NN/1024)

typedef unsigned int u32;
typedef unsigned short u16;

// ---- workspace layout (bytes) ----
// ctrl ints: [0..783] fine_hist, [784..1567] fine_off, [1568..2351] fine_cur,
//            [2352..2451] coarse_cur
static constexpr size_t OFF_CTRL = 0;
static constexpr size_t OFF_P2   = 1u << 20;                       // NE u32 (6.4 MB)
static constexpr size_t OFF_YB0  = 8u << 20;                       // NN*64 bf16 (12.8 MB)
static constexpr size_t OFF_YB1  = OFF_YB0 + (size_t)NN * 64 * 2;
static constexpr size_t OFF_U    = OFF_YB1 + (size_t)NN * 64 * 2;  // NN*64 f32 (25.6 MB)
static constexpr size_t OFF_P1   = OFF_U;                          // alias: pairs1 dead before u live
// end = 59,588,608 bytes (same footprint as R1/R2)

__device__ __forceinline__ u16 f2bf(float f) {
  u32 u = __float_as_uint(f);
  return (u16)((u + 0x7fffu + ((u >> 16) & 1u)) >> 16);
}
__device__ __forceinline__ float bflo(u32 u) { return __uint_as_float(u << 16); }
__device__ __forceinline__ float bfhi(u32 u) { return __uint_as_float(u & 0xffff0000u); }
__device__ __forceinline__ u32 pkbf(float lo, float hi) {
  return (u32)f2bf(lo) | ((u32)f2bf(hi) << 16);
}

// ---------------- pass 1: fine-bucket histogram ----------------
__global__ void __launch_bounds__(256) k_hist(const int* __restrict__ dst,
                                              int* __restrict__ fine_hist) {
  __shared__ int h[NFINE];
  for (int i = threadIdx.x; i < NFINE; i += 256) h[i] = 0;
  __syncthreads();
  int i = blockIdx.x * 256 + threadIdx.x, stride = gridDim.x * 256;
  for (; i < NE; i += stride) atomicAdd(&h[dst[i] >> 7], 1);
  __syncthreads();
  for (int i2 = threadIdx.x; i2 < NFINE; i2 += 256)
    if (h[i2]) atomicAdd(&fine_hist[i2], h[i2]);
}

// ---------------- pass 2: scan fine hist -> offsets/cursors ----------------
__global__ void __launch_bounds__(256) k_scanB(const int* __restrict__ fine_hist,
                                               int* __restrict__ fine_off,
                                               int* __restrict__ fine_cur,
                                               int* __restrict__ coarse_cur) {
  __shared__ int sd[256];
  __shared__ int carry;
  int t = threadIdx.x;
  if (t == 0) carry = 0;
  __syncthreads();
  for (int c0 = 0; c0 < 1024; c0 += 256) {
    int idx = c0 + t;
    int v = (idx < NFINE) ? fine_hist[idx] : 0;
    sd[t] = v; __syncthreads();
    for (int o = 1; o < 256; o <<= 1) {
      int x = (t >= o) ? sd[t - o] : 0;
      __syncthreads();
      sd[t] += x;
      __syncthreads();
    }
    int excl = carry + sd[t] - v;
    if (idx < NFINE) { fine_off[idx] = excl; fine_cur[idx] = excl; }
    __syncthreads();
    if (t == 255) carry += sd[255];
    __syncthreads();
  }
  if (t == 0) fine_off[NFINE] = NE;
  __syncthreads();
  if (t < NCOARSE) coarse_cur[t] = fine_off[t * 8];
}

// ---------------- pass 3: coarse scatter (LDS-batched reservation) ----------------
#define SC_CH 2048
__global__ void __launch_bounds__(256) k_scat1(const int* __restrict__ src,
                                               const int* __restrict__ dst,
                                               int* __restrict__ coarse_cur,
                                               u32* __restrict__ pairs1) {
  __shared__ int h[NCOARSE], base[NCOARSE];
  int t = threadIdx.x;
  int e0 = blockIdx.x * SC_CH;
  if (t < NCOARSE) h[t] = 0;
  __syncthreads();
  int myc[8]; u32 mypk[8];
#pragma unroll
  for (int q = 0; q < 8; q++) {
    int e = e0 + q * 256 + t;
    if (e < NE) {
      int d = dst[e], s = src[e];
      myc[q] = d >> 10;
      mypk[q] = (u32)s | ((u32)(d & 1023) << 17);
      atomicAdd(&h[myc[q]], 1);
    } else myc[q] = -1;
  }
  __syncthreads();
  if (t < NCOARSE) {
    base[t] = (h[t] > 0) ? atomicAdd(&coarse_cur[t], h[t]) : 0;
    h[t] = 0;
  }
  __syncthreads();
#pragma unroll
  for (int q = 0; q < 8; q++) {
    if (myc[q] >= 0) {
      int p = atomicAdd(&h[myc[q]], 1);
      pairs1[base[myc[q]] + p] = mypk[q];
    }
  }
}

// ---------------- pass 4: fine scatter ----------------
__global__ void __launch_bounds__(256) k_scat2(const u32* __restrict__ pairs1,
                                               const int* __restrict__ fine_off,
                                               int* __restrict__ fine_cur,
                                               u32* __restrict__ pairs2) {
  __shared__ int co[NCOARSE + 1];
  int t = threadIdx.x;
  if (t < NCOARSE) co[t] = fine_off[t * 8];
  if (t == NCOARSE) co[NCOARSE] = NE;
  __syncthreads();
  int i = blockIdx.x * 256 + t, stride = gridDim.x * 256;
  for (; i < NE; i += stride) {
    u32 pk = pairs1[i];
    int dl10 = (pk >> 17) & 1023;
    int lo = 0, hi = NCOARSE;
    while (hi - lo > 1) { int mid = (lo + hi) >> 1; if (co[mid] <= i) lo = mid; else hi = mid; }
    int f = lo * 8 + (dl10 >> 7);
    int p = atomicAdd(&fine_cur[f], 1);
    pairs2[p] = (pk & 0x1FFFFu) | ((u32)(dl10 & 127) << 17);
  }
}

// ---------------- yb0 = bf16(x @ c1_w1)  (K=128) ----------------
__global__ void __launch_bounds__(256) k_gemm_x(const float* __restrict__ x,
                                                const float* __restrict__ w,
                                                u16* __restrict__ yb) {
  __shared__ float lw[128 * 64];
  __shared__ float lx[4][128];
  int tid = threadIdx.x;
  for (int i = tid; i < 128 * 64 / 4; i += 256)
    ((float4*)lw)[i] = ((const float4*)w)[i];
  __syncthreads();
  int wid = tid >> 6, lane = tid & 63;
  for (int n0 = blockIdx.x * 4; n0 < NN; n0 += gridDim.x * 4) {
    int node = n0 + wid;
    bool valid = node < NN;
    if (valid) {
      lx[wid][lane]      = x[(size_t)node * 128 + lane];
      lx[wid][64 + lane] = x[(size_t)node * 128 + 64 + lane];
    }
    __syncthreads();
    if (valid) {
      float a0 = 0, a1 = 0, a2 = 0, a3 = 0;
      for (int k = 0; k < 128; k += 4) {
        a0 = fmaf(lx[wid][k + 0], lw[(k + 0) * 64 + lane], a0);
        a1 = fmaf(lx[wid][k + 1], lw[(k + 1) * 64 + lane], a1);
        a2 = fmaf(lx[wid][k + 2], lw[(k + 2) * 64 + lane], a2);
        a3 = fmaf(lx[wid][k + 3], lw[(k + 3) * 64 + lane], a3);
      }
      yb[(size_t)node * 64 + lane] = f2bf((a0 + a1) + (a2 + a3));
    }
    __syncthreads();
  }
}

// ---------------- aggregation from bucket-sorted edges ----------------
// block = fine bucket (128 nodes); fp32 acc in LDS; lane = feature
__global__ void __launch_bounds__(256) k_agg2(
    const u16* __restrict__ yb, const u32* __restrict__ pairs2,
    const int* __restrict__ fine_off,
    const float* __restrict__ epsv, int ei, const float* __restrict__ b1,
    float* __restrict__ u) {
  __shared__ float acc[128][64];
  int tid = threadIdx.x, lane = tid & 63, w = tid >> 6;
  int b = blockIdx.x;
  float4* av = (float4*)acc;
  for (int i = tid; i < 2048; i += 256) av[i] = make_float4(0.f, 0.f, 0.f, 0.f);
  __syncthreads();
  int es = fine_off[b], ee = fine_off[b + 1];
  for (int base = es + w * 64; base < ee; base += 256) {
    int cnt = ee - base; if (cnt > 64) cnt = 64;
    u32 pkv = (lane < cnt) ? pairs2[base + lane] : 0u;
    int j = 0;
    for (; j + 8 <= cnt; j += 8) {
      float vals[8]; int dls[8];
#pragma unroll
      for (int q = 0; q < 8; q++) {
        u32 pk = __shfl(pkv, j + q);
        int s = pk & 0x1FFFF;
        dls[q] = (pk >> 17) & 127;
        vals[q] = __uint_as_float((u32)yb[(size_t)s * 64 + lane] << 16);
      }
#pragma unroll
      for (int q = 0; q < 8; q++) atomicAdd(&acc[dls[q]][lane], vals[q]);
    }
    for (; j < cnt; j++) {
      u32 pk = __shfl(pkv, j);
      int s = pk & 0x1FFFF;
      int dl = (pk >> 17) & 127;
      float v = __uint_as_float((u32)yb[(size_t)s * 64 + lane] << 16);
      atomicAdd(&acc[dl][lane], v);
    }
  }
  __syncthreads();
  float e1 = 1.0f + epsv[ei];
  float bb = b1[lane];
  int n0 = b * 128;
  for (int r = w; r < 128; r += 4) {
    int n = n0 + r;
    if (n < NN) {
      float selfv = __uint_as_float((u32)yb[(size_t)n * 64 + lane] << 16);
      float vv = fmaxf(fmaf(e1, selfv, acc[r][lane] + bb), 0.f);
      u[(size_t)n * 64 + lane] = vv;
    }
  }
}

// ---------------- MLP: yout = bf16( BN(relu(u@w2+b2)) @ wn ) ----------------
__global__ void __launch_bounds__(256) k_mlp(
    const float* __restrict__ u, const float* __restrict__ w2, const float* __restrict__ b2,
    const float* __restrict__ gamma, const float* __restrict__ beta,
    const float* __restrict__ mean, const float* __restrict__ var,
    const float* __restrict__ wn, u16* __restrict__ yout) {
  __shared__ float lw2[64 * 64];
  __shared__ float lwn[64 * 64];
  __shared__ float ut[4][32][68];
  int tid = threadIdx.x;
  for (int idx = tid; idx < 1024; idx += 256) {
    ((float4*)lw2)[idx] = ((const float4*)w2)[idx];
    ((float4*)lwn)[idx] = ((const float4*)wn)[idx];
  }
  __syncthreads();
  int wid = tid >> 6, lane = tid & 63;
  int ng = lane >> 3, jg = lane & 7;
  int jb = jg * 8;
  int tile = blockIdx.x * 4 + wid;
  if (tile >= NN / 32) return;
  float gl[8], be[8], mn[8], rv[8], bb[8];
#pragma unroll
  for (int jj = 0; jj < 8; jj++) {
    int j = jb + jj;
    gl[jj] = gamma[j]; be[jj] = beta[j]; mn[jj] = mean[j];
    rv[jj] = rsqrtf(var[j] + BN_EPS); bb[jj] = b2[j];
  }
  int n0 = tile * 32;
  int r4 = lane >> 4;
  int k0 = (lane & 15) * 4;
  const float* ug = u + (size_t)n0 * 64;
#pragma unroll
  for (int p = 0; p < 8; p++) {
    float4 val = *(const float4*)(ug + (size_t)(p * 4 + r4) * 64 + k0);
    *(float4*)&ut[wid][p * 4 + r4][k0] = val;
  }
  float acc[4][8];
#pragma unroll
  for (int c = 0; c < 4; c++)
#pragma unroll
    for (int jj = 0; jj < 8; jj++) acc[c][jj] = 0.f;
#pragma unroll 4
  for (int k = 0; k < 64; k++) {
    float4 wA = *(const float4*)&lw2[k * 64 + jb];
    float4 wB = *(const float4*)&lw2[k * 64 + jb + 4];
    float uv[4];
#pragma unroll
    for (int c = 0; c < 4; c++) uv[c] = ut[wid][ng * 4 + c][k];
#pragma unroll
    for (int c = 0; c < 4; c++) {
      acc[c][0] = fmaf(uv[c], wA.x, acc[c][0]);
      acc[c][1] = fmaf(uv[c], wA.y, acc[c][1]);
      acc[c][2] = fmaf(uv[c], wA.z, acc[c][2]);
      acc[c][3] = fmaf(uv[c], wA.w, acc[c][3]);
      acc[c][4] = fmaf(uv[c], wB.x, acc[c][4]);
      acc[c][5] = fmaf(uv[c], wB.y, acc[c][5]);
      acc[c][6] = fmaf(uv[c], wB.z, acc[c][6]);
      acc[c][7] = fmaf(uv[c], wB.w, acc[c][7]);
    }
  }
#pragma unroll
  for (int c = 0; c < 4; c++) {
    float h[8];
#pragma unroll
    for (int jj = 0; jj < 8; jj++) {
      float v = fmaxf(acc[c][jj] + bb[jj], 0.f);
      h[jj] = fmaf(gl[jj] * (v - mn[jj]), rv[jj], be[jj]);
    }
    *(float4*)&ut[wid][ng * 4 + c][jb]     = make_float4(h[0], h[1], h[2], h[3]);
    *(float4*)&ut[wid][ng * 4 + c][jb + 4] = make_float4(h[4], h[5], h[6], h[7]);
  }
  float ac2[4][8];
#pragma unroll
  for (int c = 0; c < 4; c++)
#pragma unroll
    for (int jj = 0; jj < 8; jj++) ac2[c][jj] = 0.f;
#pragma unroll 4
  for (int k = 0; k < 64; k++) {
    float4 wA = *(const float4*)&lwn[k * 64 + jb];
    float4 wB = *(const float4*)&lwn[k * 64 + jb + 4];
    float uv[4];
#pragma unroll
    for (int c = 0; c < 4; c++) uv[c] = ut[wid][ng * 4 + c][k];
#pragma unroll
    for (int c = 0; c < 4; c++) {
      ac2[c][0] = fmaf(uv[c], wA.x, ac2[c][0]);
      ac2[c][1] = fmaf(uv[c], wA.y, ac2[c][1]);
      ac2[c][2] = fmaf(uv[c], wA.z, ac2[c][2]);
      ac2[c][3] = fmaf(uv[c], wA.w, ac2[c][3]);
      ac2[c][4] = fmaf(uv[c], wB.x, ac2[c][4]);
      ac2[c][5] = fmaf(uv[c], wB.y, ac2[c][5]);
      ac2[c][6] = fmaf(uv[c], wB.z, ac2[c][6]);
      ac2[c][7] = fmaf(uv[c], wB.w, ac2[c][7]);
    }
  }
#pragma unroll
  for (int c = 0; c < 4; c++) {
    int n = n0 + ng * 4 + c;
    uint4 pk;
    pk.x = pkbf(ac2[c][0], ac2[c][1]);
    pk.y = pkbf(ac2[c][2], ac2[c][3]);
    pk.z = pkbf(ac2[c][4], ac2[c][5]);
    pk.w = pkbf(ac2[c][6], ac2[c][7]);
    *(uint4*)(yout + (size_t)n * 64 + jb) = pk;
  }
}

// ---------------- final MLP + head ----------------
__global__ void __launch_bounds__(256) k_mlp_final(
    const float* __restrict__ u, const float* __restrict__ w2, const float* __restrict__ b2,
    const float* __restrict__ gamma, const float* __restrict__ beta,
    const float* __restrict__ mean, const float* __restrict__ var,
    const float* __restrict__ l1w, const float* __restrict__ l1b,
    const float* __restrict__ l2w, const float* __restrict__ l2b,
    float* __restrict__ out) {
  __shared__ float lw2[64 * 64];
  __shared__ float lh1[64 * 64];
  __shared__ float lh2[64 * 40];
  __shared__ float ut[4][32][68];
  int tid = threadIdx.x;
  for (int idx = tid; idx < 1024; idx += 256) {
    ((float4*)lw2)[idx] = ((const float4*)w2)[idx];
    ((float4*)lh1)[idx] = ((const float4*)l1w)[idx];
  }
  for (int idx = tid; idx < 640; idx += 256) ((float4*)lh2)[idx] = ((const float4*)l2w)[idx];
  __syncthreads();
  int tid2 = threadIdx.x;
  int wid = tid2 >> 6, lane = tid2 & 63;
  int ng = lane >> 3, jg = lane & 7;
  int jb = jg * 8;
  int tile = blockIdx.x * 4 + wid;
  if (tile >= NN / 32) return;
  float gl[8], be[8], mn[8], rv[8], bb[8], lb[8];
#pragma unroll
  for (int jj = 0; jj < 8; jj++) {
    int j = jb + jj;
    gl[jj] = gamma[j]; be[jj] = beta[j]; mn[jj] = mean[j];
    rv[jj] = rsqrtf(var[j] + BN_EPS); bb[jj] = b2[j]; lb[jj] = l1b[j];
  }
  float l2bv[5];
#pragma unroll
  for (int jj = 0; jj < 5; jj++) l2bv[jj] = l2b[jg * 5 + jj];
  int n0 = tile * 32;
  int r4 = lane >> 4;
  int k0 = (lane & 15) * 4;
  const float* ug = u + (size_t)n0 * 64;
#pragma unroll
  for (int p = 0; p < 8; p++) {
    float4 val = *(const float4*)(ug + (size_t)(p * 4 + r4) * 64 + k0);
    *(float4*)&ut[wid][p * 4 + r4][k0] = val;
  }
  float acc[4][8];
#pragma unroll
  for (int c = 0; c < 4; c++)
#pragma unroll
    for (int jj = 0; jj < 8; jj++) acc[c][jj] = 0.f;
#pragma unroll 4
  for (int k = 0; k < 64; k++) {
    float4 wA = *(const float4*)&lw2[k * 64 + jb];
    float4 wB = *(const float4*)&lw2[k * 64 + jb + 4];
    float uv[4];
#pragma unroll
    for (int c = 0; c < 4; c++) uv[c] = ut[wid][ng * 4 + c][k];
#pragma unroll
    for (int c = 0; c < 4; c++) {
      acc[c][0] = fmaf(uv[c], wA.x, acc[c][0]);
      acc[c][1] = fmaf(uv[c], wA.y, acc[c][1]);
      acc[c][2] = fmaf(uv[c], wA.z, acc[c][2]);
      acc[c][3] = fmaf(uv[c], wA.w, acc[c][3]);
      acc[c][4] = fmaf(uv[c], wB.x, acc[c][4]);
      acc[c][5] = fmaf(uv[c], wB.y, acc[c][5]);
      acc[c][6] = fmaf(uv[c], wB.z, acc[c][6]);
      acc[c][7] = fmaf(uv[c], wB.w, acc[c][7]);
    }
  }
#pragma unroll
  for (int c = 0; c < 4; c++) {
    float h[8];
#pragma unroll
    for (int jj = 0; jj < 8; jj++) {
      float v = fmaxf(acc[c][jj] + bb[jj], 0.f);
      h[jj] = fmaf(gl[jj] * (v - mn[jj]), rv[jj], be[jj]);
    }
    *(float4*)&ut[wid][ng * 4 + c][jb]     = make_float4(h[0], h[1], h[2], h[3]);
    *(float4*)&ut[wid][ng * 4 + c][jb + 4] = make_float4(h[4], h[5], h[6], h[7]);
  }
  float ac2[4][8];
#pragma unroll
  for (int c = 0; c < 4; c++)
#pragma unroll
    for (int jj = 0; jj < 8; jj++) ac2[c][jj] = 0.f;
#pragma unroll 4
  for (int k = 0; k < 64; k++) {
    float4 wA = *(const float4*)&lh1[k * 64 + jb];
    float4 wB = *(const float4*)&lh1[k * 64 + jb + 4];
    float uv[4];
#pragma unroll
    for (int c = 0; c < 4; c++) uv[c] = ut[wid][ng * 4 + c][k];
#pragma unroll
    for (int c = 0; c < 4; c++) {
      ac2[c][0] = fmaf(uv[c], wA.x, ac2[c][0]);
      ac2[c][1] = fmaf(uv[c], wA.y, ac2[c][1]);
      ac2[c][2] = fmaf(uv[c], wA.z, ac2[c][2]);
      ac2[c][3] = fmaf(uv[c], wA.w, ac2[c][3]);
      ac2[c][4] = fmaf(uv[c], wB.x, ac2[c][4]);
      ac2[c][5] = fmaf(uv[c], wB.y, ac2[c][5]);
      ac2[c][6] = fmaf(uv[c], wB.z, ac2[c][6]);
      ac2[c][7] = fmaf(uv[c], wB.w, ac2[c][7]);
    }
  }
#pragma unroll
  for (int c = 0; c < 4; c++) {
    float f0 = fmaxf(ac2[c][0] + lb[0], 0.f), f1 = fmaxf(ac2[c][1] + lb[1], 0.f);
    float f2 = fmaxf(ac2[c][2] + lb[2], 0.f), f3 = fmaxf(ac2[c][3] + lb[3], 0.f);
    float f4 = fmaxf(ac2[c][4] + lb[4], 0.f), f5 = fmaxf(ac2[c][5] + lb[5], 0.f);
    float f6 = fmaxf(ac2[c][6] + lb[6], 0.f), f7 = fmaxf(ac2[c][7] + lb[7], 0.f);
    *(float4*)&ut[wid][ng * 4 + c][jb]     = make_float4(f0, f1, f2, f3);
    *(float4*)&ut[wid][ng * 4 + c][jb + 4] = make_float4(f4, f5, f6, f7);
  }
  float ac3[4][5];
#pragma unroll
  for (int c = 0; c < 4; c++)
#pragma unroll
    for (int jj = 0; jj < 5; jj++) ac3[c][jj] = 0.f;
#pragma unroll 4
  for (int k = 0; k < 64; k++) {
    float wv[5];
#pragma unroll
    for (int jj = 0; jj < 5; jj++) wv[jj] = lh2[k * 40 + jg * 5 + jj];
    float uv[4];
#pragma unroll
    for (int c = 0; c < 4; c++) uv[c] = ut[wid][ng * 4 + c][k];
#pragma unroll
    for (int c = 0; c < 4; c++)
#pragma unroll
      for (int jj = 0; jj < 5; jj++) ac3[c][jj] = fmaf(uv[c], wv[jj], ac3[c][jj]);
  }
#pragma unroll
  for (int c = 0; c < 4; c++) {
    int n = n0 + ng * 4 + c;
#pragma unroll
    for (int jj = 0; jj < 5; jj++)
      out[(size_t)n * 40 + jg * 5 + jj] = ac3[c][jj] + l2bv[jj];
  }
}

extern "C" void kernel_launch(void* const* d_in, const int* in_sizes, int n_in,
                              void* d_out, int out_size, void* d_ws, size_t ws_size,
                              hipStream_t stream) {
  const float* x   = (const float*)d_in[0];
  const int*   ei  = (const int*)d_in[1];
  const int*   src = ei;
  const int*   dst = ei + NE;
  const float* eps = (const float*)d_in[2];
  const float* c1_w1 = (const float*)d_in[3];
  const float* c1_b1 = (const float*)d_in[4];
  const float* c1_w2 = (const float*)d_in[5];
  const float* c1_b2 = (const float*)d_in[6];
  const float* c1_gamma = (const float*)d_in[7];
  const float* c1_beta  = (const float*)d_in[8];
  const float* c1_mean  = (const float*)d_in[9];
  const float* c1_var   = (const float*)d_in[10];
  const float* cw1 = (const float*)d_in[11];
  const float* cb1 = (const float*)d_in[12];
  const float* cw2 = (const float*)d_in[13];
  const float* cb2 = (const float*)d_in[14];
  const float* cgamma = (const float*)d_in[15];
  const float* cbeta  = (const float*)d_in[16];
  const float* cmean  = (const float*)d_in[17];
  const float* cvar   = (const float*)d_in[18];
  const float* lin1_w = (const float*)d_in[19];
  const float* lin1_b = (const float*)d_in[20];
  const float* lin2_w = (const float*)d_in[21];
  const float* lin2_b = (const float*)d_in[22];
  float* out = (float*)d_out;

  char* ws = (char*)d_ws;
  int* ctrl      = (int*)(ws + OFF_CTRL);
  int* fine_hist = ctrl;
  int* fine_off  = ctrl + 784;
  int* fine_cur  = ctrl + 1568;
  int* coarse_cur= ctrl + 2352;
  u32* pairs2 = (u32*)(ws + OFF_P2);
  u32* pairs1 = (u32*)(ws + OFF_P1);
  float* u  = (float*)(ws + OFF_U);
  u16* yb0  = (u16*)(ws + OFF_YB0);
  u16* yb1  = (u16*)(ws + OFF_YB1);

  hipMemsetAsync(fine_hist, 0, 784 * 4, stream);

  k_hist<<<1024, 256, 0, stream>>>(dst, fine_hist);
  k_scanB<<<1, 256, 0, stream>>>(fine_hist, fine_off, fine_cur, coarse_cur);
  k_scat1<<<(NE + SC_CH - 1) / SC_CH, 256, 0, stream>>>(src, dst, coarse_cur, pairs1);
  k_scat2<<<NFINE, 256, 0, stream>>>(pairs1, fine_off, fine_cur, pairs2);

  // y0 = bf16(x @ c1_w1)
  k_gemm_x<<<2048, 256, 0, stream>>>(x, c1_w1, yb0);

  const int MLP_GRID = (NN / 32 + 3) / 4;

  // layer 1
  k_agg2<<<NFINE, 256, 0, stream>>>(yb0, pairs2, fine_off, eps, 0, c1_b1, u);
  k_mlp<<<MLP_GRID, 256, 0, stream>>>(u, c1_w2, c1_b2,
                                      c1_gamma, c1_beta, c1_mean, c1_var,
                                      cw1, yb1);
  // layer 2
  k_agg2<<<NFINE, 256, 0, stream>>>(yb1, pairs2, fine_off, eps, 1, cb1, u);
  k_mlp<<<MLP_GRID, 256, 0, stream>>>(u, cw2, cb2,
                                      cgamma, cbeta, cmean, cvar,
                                      cw1 + 64 * 64, yb0);
  // layer 3 + head
  k_agg2<<<NFINE, 256, 0, stream>>>(yb0, pairs2, fine_off, eps, 2, cb1 + 64, u);
  k_mlp_final<<<MLP_GRID, 256, 0, stream>>>(u, cw2 + 64 * 64, cb2 + 64,
                                            cgamma + 64, cbeta + 64, cmean + 64, cvar + 64,
                                            lin1_w, lin1_b, lin2_w, lin2_b,
                                            out);
}

// Round 4
// 370.561 us; speedup vs baseline: 8.1322x; 8.1322x over previous
//
#include <hip/hip_runtime.h>

#define NN 100000
#define NE 1600000
#define BN_EPS 1e-5f
#define NCOARSE 98   // ceil(NN/1024)
#define SC_CH 2048

typedef unsigned int u32;
typedef unsigned short u16;

// ---- workspace layout (bytes) ----
static constexpr size_t OFF_ROW  = 0;                    // (NN+1) ints
static constexpr size_t OFF_CTRL = 512u * 1024;          // ch[98], coff[99], ccur[98]
static constexpr size_t OFF_CSR  = 1u << 20;             // NE ints (6.4 MB) -> ends 7.4 MB
static constexpr size_t OFF_U    = 8u << 20;             // NN*64 f32 (25.6 MB)
static constexpr size_t OFF_P1   = OFF_U;                // alias: pairs1 dead before u live
static constexpr size_t OFF_YB0  = OFF_U + (size_t)NN * 64 * 4;   // 33,988,608
static constexpr size_t OFF_YB1  = OFF_YB0 + (size_t)NN * 64 * 2; // 46,788,608
// end = 59,588,608 bytes — same footprint as R1/R2

__device__ __forceinline__ u16 f2bf(float f) {
  u32 u = __float_as_uint(f);
  return (u16)((u + 0x7fffu + ((u >> 16) & 1u)) >> 16);
}
__device__ __forceinline__ float bflo(u32 u) { return __uint_as_float(u << 16); }
__device__ __forceinline__ float bfhi(u32 u) { return __uint_as_float(u & 0xffff0000u); }
__device__ __forceinline__ u32 pkbf(float lo, float hi) {
  return (u32)f2bf(lo) | ((u32)f2bf(hi) << 16);
}

// ---------------- pass 1: coarse histogram (98 buckets of 1024 nodes) ----------------
__global__ void __launch_bounds__(256) k_hist_c(const int* __restrict__ dst,
                                                int* __restrict__ ch) {
  __shared__ int h[NCOARSE];
  if (threadIdx.x < NCOARSE) h[threadIdx.x] = 0;
  __syncthreads();
  int i = blockIdx.x * 256 + threadIdx.x, stride = gridDim.x * 256;
  for (; i < NE; i += stride) atomicAdd(&h[dst[i] >> 10], 1);
  __syncthreads();
  if (threadIdx.x < NCOARSE && h[threadIdx.x]) atomicAdd(&ch[threadIdx.x], h[threadIdx.x]);
}

// ---------------- pass 2: scan 98 coarse counts ----------------
__global__ void k_scan_c(const int* __restrict__ ch, int* __restrict__ coff,
                         int* __restrict__ ccur) {
  if (threadIdx.x == 0) {
    int acc = 0;
    for (int i = 0; i < NCOARSE; i++) { coff[i] = acc; ccur[i] = acc; acc += ch[i]; }
    coff[NCOARSE] = acc;   // == NE
  }
}

// ---------------- pass 3: coarse scatter (LDS-batched reservation) ----------------
// pack: src (17 bits) | (dst & 1023) << 17
__global__ void __launch_bounds__(256) k_scat1(const int* __restrict__ src,
                                               const int* __restrict__ dst,
                                               int* __restrict__ ccur,
                                               u32* __restrict__ pairs1) {
  __shared__ int h[NCOARSE], base[NCOARSE];
  int t = threadIdx.x;
  int e0 = blockIdx.x * SC_CH;
  if (t < NCOARSE) h[t] = 0;
  __syncthreads();
  int myc[8]; u32 mypk[8];
#pragma unroll
  for (int q = 0; q < 8; q++) {
    int e = e0 + q * 256 + t;
    if (e < NE) {
      int d = dst[e], s = src[e];
      myc[q] = d >> 10;
      mypk[q] = (u32)s | ((u32)(d & 1023) << 17);
      atomicAdd(&h[myc[q]], 1);
    } else myc[q] = -1;
  }
  __syncthreads();
  if (t < NCOARSE) {
    base[t] = (h[t] > 0) ? atomicAdd(&ccur[t], h[t]) : 0;
    h[t] = 0;
  }
  __syncthreads();
#pragma unroll
  for (int q = 0; q < 8; q++) {
    if (myc[q] >= 0) {
      int p = atomicAdd(&h[myc[q]], 1);
      pairs1[base[myc[q]] + p] = mypk[q];
    }
  }
}

// ---------------- pass 4: per-bucket CSR build, all in LDS ----------------
// block = coarse bucket: count 1024 nodes, scan, scatter into LDS stage, stream out.
__global__ void __launch_bounds__(256) k_fill3(const u32* __restrict__ pairs1,
                                               const int* __restrict__ coff,
                                               int* __restrict__ row,
                                               int* __restrict__ csr) {
  __shared__ int lcnt[1024];
  __shared__ int loff[1024];
  __shared__ int sd[256];
  __shared__ u32 stage[20480];   // 80 KB; avg bucket ~16.3K edges, max ~17K
  int c = blockIdx.x, t = threadIdx.x;
  int es = coff[c], ee = coff[c + 1];
  int m = ee - es;
  int nbase = c << 10;
  int nodes_in = NN - nbase; if (nodes_in > 1024) nodes_in = 1024;
  for (int i = t; i < 1024; i += 256) lcnt[i] = 0;
  __syncthreads();
  for (int i = es + t; i < ee; i += 256)
    atomicAdd(&lcnt[(pairs1[i] >> 17) & 1023], 1);
  __syncthreads();
  int b4 = t * 4;
  int c0 = lcnt[b4], c1 = lcnt[b4 + 1], c2 = lcnt[b4 + 2], c3 = lcnt[b4 + 3];
  int s4 = c0 + c1 + c2 + c3;
  sd[t] = s4;
  __syncthreads();
  for (int o = 1; o < 256; o <<= 1) {
    int x = (t >= o) ? sd[t - o] : 0;
    __syncthreads();
    sd[t] += x;
    __syncthreads();
  }
  int run = sd[t] - s4;
  loff[b4] = run;     run += c0;
  loff[b4 + 1] = run; run += c1;
  loff[b4 + 2] = run; run += c2;
  loff[b4 + 3] = run;
  __syncthreads();
  for (int i = t; i < nodes_in; i += 256) row[nbase + i] = es + loff[i];
  if (c == NCOARSE - 1 && t == 0) row[NN] = NE;
  for (int i = t; i < 1024; i += 256) lcnt[i] = loff[i];   // lcnt becomes cursor
  __syncthreads();
  if (m <= 20480) {
    for (int i = es + t; i < ee; i += 256) {
      u32 pk = pairs1[i];
      int p = atomicAdd(&lcnt[(pk >> 17) & 1023], 1);
      stage[p] = pk & 0x1FFFFu;
    }
    __syncthreads();
    for (int i = t; i < m; i += 256) csr[es + i] = (int)stage[i];
  } else {   // defensive fallback (never expected for this input)
    for (int i = es + t; i < ee; i += 256) {
      u32 pk = pairs1[i];
      int p = atomicAdd(&lcnt[(pk >> 17) & 1023], 1);
      csr[es + p] = (int)(pk & 0x1FFFFu);
    }
  }
}

// ---------------- yb0 = bf16(x @ c1_w1)  (K=128) ----------------
__global__ void __launch_bounds__(256) k_gemm_x(const float* __restrict__ x,
                                                const float* __restrict__ w,
                                                u16* __restrict__ yb) {
  __shared__ float lw[128 * 64];
  __shared__ float lx[4][128];
  int tid = threadIdx.x;
  for (int i = tid; i < 128 * 64 / 4; i += 256)
    ((float4*)lw)[i] = ((const float4*)w)[i];
  __syncthreads();
  int wid = tid >> 6, lane = tid & 63;
  for (int n0 = blockIdx.x * 4; n0 < NN; n0 += gridDim.x * 4) {
    int node = n0 + wid;
    bool valid = node < NN;
    if (valid) {
      lx[wid][lane]      = x[(size_t)node * 128 + lane];
      lx[wid][64 + lane] = x[(size_t)node * 128 + 64 + lane];
    }
    __syncthreads();
    if (valid) {
      float a0 = 0, a1 = 0, a2 = 0, a3 = 0;
      for (int k = 0; k < 128; k += 4) {
        a0 = fmaf(lx[wid][k + 0], lw[(k + 0) * 64 + lane], a0);
        a1 = fmaf(lx[wid][k + 1], lw[(k + 1) * 64 + lane], a1);
        a2 = fmaf(lx[wid][k + 2], lw[(k + 2) * 64 + lane], a2);
        a3 = fmaf(lx[wid][k + 3], lw[(k + 3) * 64 + lane], a3);
      }
      yb[(size_t)node * 64 + lane] = f2bf((a0 + a1) + (a2 + a3));
    }
    __syncthreads();
  }
}

// ---------------- aggregation: u = relu((1+eps)*y + sum_nbr y + b1) ----------------
// thread = (node, feature-octet); register accumulate; 8 gathers in flight.
__global__ void __launch_bounds__(256) k_agg(
    const u16* __restrict__ yb, const int* __restrict__ row, const int* __restrict__ csr,
    const float* __restrict__ epsv, int ei, const float* __restrict__ b1,
    float* __restrict__ u) {
  int t = blockIdx.x * 256 + threadIdx.x;
  int n = t >> 3, g = t & 7;
  if (n >= NN) return;
  const u16* bp = yb + g * 8;
  float a0 = 0, a1 = 0, a2 = 0, a3 = 0, a4 = 0, a5 = 0, a6 = 0, a7 = 0;
  int rs = row[n], re = row[n + 1];
  int i = rs;
  for (; i + 8 <= re; i += 8) {
    uint4 v[8];
#pragma unroll
    for (int q = 0; q < 8; q++) {
      int s = csr[i + q];
      v[q] = *(const uint4*)(bp + (size_t)s * 64);
    }
#pragma unroll
    for (int q = 0; q < 8; q++) {
      a0 += bflo(v[q].x); a1 += bfhi(v[q].x); a2 += bflo(v[q].y); a3 += bfhi(v[q].y);
      a4 += bflo(v[q].z); a5 += bfhi(v[q].z); a6 += bflo(v[q].w); a7 += bfhi(v[q].w);
    }
  }
  for (; i + 4 <= re; i += 4) {
    uint4 v[4];
#pragma unroll
    for (int q = 0; q < 4; q++) {
      int s = csr[i + q];
      v[q] = *(const uint4*)(bp + (size_t)s * 64);
    }
#pragma unroll
    for (int q = 0; q < 4; q++) {
      a0 += bflo(v[q].x); a1 += bfhi(v[q].x); a2 += bflo(v[q].y); a3 += bfhi(v[q].y);
      a4 += bflo(v[q].z); a5 += bfhi(v[q].z); a6 += bflo(v[q].w); a7 += bfhi(v[q].w);
    }
  }
  for (; i < re; ++i) {
    int s = csr[i];
    uint4 v0 = *(const uint4*)(bp + (size_t)s * 64);
    a0 += bflo(v0.x); a1 += bfhi(v0.x); a2 += bflo(v0.y); a3 += bfhi(v0.y);
    a4 += bflo(v0.z); a5 += bfhi(v0.z); a6 += bflo(v0.w); a7 += bfhi(v0.w);
  }
  uint4 sv = *(const uint4*)(bp + (size_t)n * 64);
  float e1 = 1.0f + epsv[ei];
  const float* bb = b1 + g * 8;
  float r0 = fmaxf(fmaf(e1, bflo(sv.x), a0 + bb[0]), 0.f);
  float r1 = fmaxf(fmaf(e1, bfhi(sv.x), a1 + bb[1]), 0.f);
  float r2 = fmaxf(fmaf(e1, bflo(sv.y), a2 + bb[2]), 0.f);
  float r3 = fmaxf(fmaf(e1, bfhi(sv.y), a3 + bb[3]), 0.f);
  float r4 = fmaxf(fmaf(e1, bflo(sv.z), a4 + bb[4]), 0.f);
  float r5 = fmaxf(fmaf(e1, bfhi(sv.z), a5 + bb[5]), 0.f);
  float r6 = fmaxf(fmaf(e1, bflo(sv.w), a6 + bb[6]), 0.f);
  float r7 = fmaxf(fmaf(e1, bfhi(sv.w), a7 + bb[7]), 0.f);
  float4* up = (float4*)(u + (size_t)n * 64 + g * 8);
  up[0] = make_float4(r0, r1, r2, r3);
  up[1] = make_float4(r4, r5, r6, r7);
}

// ---------------- MLP: yout = bf16( BN(relu(u@w2+b2)) @ wn ) ----------------
__global__ void __launch_bounds__(256) k_mlp(
    const float* __restrict__ u, const float* __restrict__ w2, const float* __restrict__ b2,
    const float* __restrict__ gamma, const float* __restrict__ beta,
    const float* __restrict__ mean, const float* __restrict__ var,
    const float* __restrict__ wn, u16* __restrict__ yout) {
  __shared__ float lw2[64 * 64];
  __shared__ float lwn[64 * 64];
  __shared__ float ut[4][32][68];
  int tid = threadIdx.x;
  for (int idx = tid; idx < 1024; idx += 256) {
    ((float4*)lw2)[idx] = ((const float4*)w2)[idx];
    ((float4*)lwn)[idx] = ((const float4*)wn)[idx];
  }
  __syncthreads();
  int wid = tid >> 6, lane = tid & 63;
  int ng = lane >> 3, jg = lane & 7;
  int jb = jg * 8;
  int tile = blockIdx.x * 4 + wid;
  if (tile >= NN / 32) return;
  float gl[8], be[8], mn[8], rv[8], bb[8];
#pragma unroll
  for (int jj = 0; jj < 8; jj++) {
    int j = jb + jj;
    gl[jj] = gamma[j]; be[jj] = beta[j]; mn[jj] = mean[j];
    rv[jj] = rsqrtf(var[j] + BN_EPS); bb[jj] = b2[j];
  }
  int n0 = tile * 32;
  int r4 = lane >> 4;
  int k0 = (lane & 15) * 4;
  const float* ug = u + (size_t)n0 * 64;
#pragma unroll
  for (int p = 0; p < 8; p++) {
    float4 val = *(const float4*)(ug + (size_t)(p * 4 + r4) * 64 + k0);
    *(float4*)&ut[wid][p * 4 + r4][k0] = val;
  }
  float acc[4][8];
#pragma unroll
  for (int c = 0; c < 4; c++)
#pragma unroll
    for (int jj = 0; jj < 8; jj++) acc[c][jj] = 0.f;
#pragma unroll 4
  for (int k = 0; k < 64; k++) {
    float4 wA = *(const float4*)&lw2[k * 64 + jb];
    float4 wB = *(const float4*)&lw2[k * 64 + jb + 4];
    float uv[4];
#pragma unroll
    for (int c = 0; c < 4; c++) uv[c] = ut[wid][ng * 4 + c][k];
#pragma unroll
    for (int c = 0; c < 4; c++) {
      acc[c][0] = fmaf(uv[c], wA.x, acc[c][0]);
      acc[c][1] = fmaf(uv[c], wA.y, acc[c][1]);
      acc[c][2] = fmaf(uv[c], wA.z, acc[c][2]);
      acc[c][3] = fmaf(uv[c], wA.w, acc[c][3]);
      acc[c][4] = fmaf(uv[c], wB.x, acc[c][4]);
      acc[c][5] = fmaf(uv[c], wB.y, acc[c][5]);
      acc[c][6] = fmaf(uv[c], wB.z, acc[c][6]);
      acc[c][7] = fmaf(uv[c], wB.w, acc[c][7]);
    }
  }
#pragma unroll
  for (int c = 0; c < 4; c++) {
    float h[8];
#pragma unroll
    for (int jj = 0; jj < 8; jj++) {
      float v = fmaxf(acc[c][jj] + bb[jj], 0.f);
      h[jj] = fmaf(gl[jj] * (v - mn[jj]), rv[jj], be[jj]);
    }
    *(float4*)&ut[wid][ng * 4 + c][jb]     = make_float4(h[0], h[1], h[2], h[3]);
    *(float4*)&ut[wid][ng * 4 + c][jb + 4] = make_float4(h[4], h[5], h[6], h[7]);
  }
  float ac2[4][8];
#pragma unroll
  for (int c = 0; c < 4; c++)
#pragma unroll
    for (int jj = 0; jj < 8; jj++) ac2[c][jj] = 0.f;
#pragma unroll 4
  for (int k = 0; k < 64; k++) {
    float4 wA = *(const float4*)&lwn[k * 64 + jb];
    float4 wB = *(const float4*)&lwn[k * 64 + jb + 4];
    float uv[4];
#pragma unroll
    for (int c = 0; c < 4; c++) uv[c] = ut[wid][ng * 4 + c][k];
#pragma unroll
    for (int c = 0; c < 4; c++) {
      ac2[c][0] = fmaf(uv[c], wA.x, ac2[c][0]);
      ac2[c][1] = fmaf(uv[c], wA.y, ac2[c][1]);
      ac2[c][2] = fmaf(uv[c], wA.z, ac2[c][2]);
      ac2[c][3] = fmaf(uv[c], wA.w, ac2[c][3]);
      ac2[c][4] = fmaf(uv[c], wB.x, ac2[c][4]);
      ac2[c][5] = fmaf(uv[c], wB.y, ac2[c][5]);
      ac2[c][6] = fmaf(uv[c], wB.z, ac2[c][6]);
      ac2[c][7] = fmaf(uv[c], wB.w, ac2[c][7]);
    }
  }
#pragma unroll
  for (int c = 0; c < 4; c++) {
    int n = n0 + ng * 4 + c;
    uint4 pk;
    pk.x = pkbf(ac2[c][0], ac2[c][1]);
    pk.y = pkbf(ac2[c][2], ac2[c][3]);
    pk.z = pkbf(ac2[c][4], ac2[c][5]);
    pk.w = pkbf(ac2[c][6], ac2[c][7]);
    *(uint4*)(yout + (size_t)n * 64 + jb) = pk;
  }
}

// ---------------- final MLP + head ----------------
__global__ void __launch_bounds__(256) k_mlp_final(
    const float* __restrict__ u, const float* __restrict__ w2, const float* __restrict__ b2,
    const float* __restrict__ gamma, const float* __restrict__ beta,
    const float* __restrict__ mean, const float* __restrict__ var,
    const float* __restrict__ l1w, const float* __restrict__ l1b,
    const float* __restrict__ l2w, const float* __restrict__ l2b,
    float* __restrict__ out) {
  __shared__ float lw2[64 * 64];
  __shared__ float lh1[64 * 64];
  __shared__ float lh2[64 * 40];
  __shared__ float ut[4][32][68];
  int tid = threadIdx.x;
  for (int idx = tid; idx < 1024; idx += 256) {
    ((float4*)lw2)[idx] = ((const float4*)w2)[idx];
    ((float4*)lh1)[idx] = ((const float4*)l1w)[idx];
  }
  for (int idx = tid; idx < 640; idx += 256) ((float4*)lh2)[idx] = ((const float4*)l2w)[idx];
  __syncthreads();
  int wid = tid >> 6, lane = tid & 63;
  int ng = lane >> 3, jg = lane & 7;
  int jb = jg * 8;
  int tile = blockIdx.x * 4 + wid;
  if (tile >= NN / 32) return;
  float gl[8], be[8], mn[8], rv[8], bb[8], lb[8];
#pragma unroll
  for (int jj = 0; jj < 8; jj++) {
    int j = jb + jj;
    gl[jj] = gamma[j]; be[jj] = beta[j]; mn[jj] = mean[j];
    rv[jj] = rsqrtf(var[j] + BN_EPS); bb[jj] = b2[j]; lb[jj] = l1b[j];
  }
  float l2bv[5];
#pragma unroll
  for (int jj = 0; jj < 5; jj++) l2bv[jj] = l2b[jg * 5 + jj];
  int n0 = tile * 32;
  int r4 = lane >> 4;
  int k0 = (lane & 15) * 4;
  const float* ug = u + (size_t)n0 * 64;
#pragma unroll
  for (int p = 0; p < 8; p++) {
    float4 val = *(const float4*)(ug + (size_t)(p * 4 + r4) * 64 + k0);
    *(float4*)&ut[wid][p * 4 + r4][k0] = val;
  }
  float acc[4][8];
#pragma unroll
  for (int c = 0; c < 4; c++)
#pragma unroll
    for (int jj = 0; jj < 8; jj++) acc[c][jj] = 0.f;
#pragma unroll 4
  for (int k = 0; k < 64; k++) {
    float4 wA = *(const float4*)&lw2[k * 64 + jb];
    float4 wB = *(const float4*)&lw2[k * 64 + jb + 4];
    float uv[4];
#pragma unroll
    for (int c = 0; c < 4; c++) uv[c] = ut[wid][ng * 4 + c][k];
#pragma unroll
    for (int c = 0; c < 4; c++) {
      acc[c][0] = fmaf(uv[c], wA.x, acc[c][0]);
      acc[c][1] = fmaf(uv[c], wA.y, acc[c][1]);
      acc[c][2] = fmaf(uv[c], wA.z, acc[c][2]);
      acc[c][3] = fmaf(uv[c], wA.w, acc[c][3]);
      acc[c][4] = fmaf(uv[c], wB.x, acc[c][4]);
      acc[c][5] = fmaf(uv[c], wB.y, acc[c][5]);
      acc[c][6] = fmaf(uv[c], wB.z, acc[c][6]);
      acc[c][7] = fmaf(uv[c], wB.w, acc[c][7]);
    }
  }
#pragma unroll
  for (int c = 0; c < 4; c++) {
    float h[8];
#pragma unroll
    for (int jj = 0; jj < 8; jj++) {
      float v = fmaxf(acc[c][jj] + bb[jj], 0.f);
      h[jj] = fmaf(gl[jj] * (v - mn[jj]), rv[jj], be[jj]);
    }
    *(float4*)&ut[wid][ng * 4 + c][jb]     = make_float4(h[0], h[1], h[2], h[3]);
    *(float4*)&ut[wid][ng * 4 + c][jb + 4] = make_float4(h[4], h[5], h[6], h[7]);
  }
  float ac2[4][8];
#pragma unroll
  for (int c = 0; c < 4; c++)
#pragma unroll
    for (int jj = 0; jj < 8; jj++) ac2[c][jj] = 0.f;
#pragma unroll 4
  for (int k = 0; k < 64; k++) {
    float4 wA = *(const float4*)&lh1[k * 64 + jb];
    float4 wB = *(const float4*)&lh1[k * 64 + jb + 4];
    float uv[4];
#pragma unroll
    for (int c = 0; c < 4; c++) uv[c] = ut[wid][ng * 4 + c][k];
#pragma unroll
    for (int c = 0; c < 4; c++) {
      ac2[c][0] = fmaf(uv[c], wA.x, ac2[c][0]);
      ac2[c][1] = fmaf(uv[c], wA.y, ac2[c][1]);
      ac2[c][2] = fmaf(uv[c], wA.z, ac2[c][2]);
      ac2[c][3] = fmaf(uv[c], wA.w, ac2[c][3]);
      ac2[c][4] = fmaf(uv[c], wB.x, ac2[c][4]);
      ac2[c][5] = fmaf(uv[c], wB.y, ac2[c][5]);
      ac2[c][6] = fmaf(uv[c], wB.z, ac2[c][6]);
      ac2[c][7] = fmaf(uv[c], wB.w, ac2[c][7]);
    }
  }
#pragma unroll
  for (int c = 0; c < 4; c++) {
    float f0 = fmaxf(ac2[c][0] + lb[0], 0.f), f1 = fmaxf(ac2[c][1] + lb[1], 0.f);
    float f2 = fmaxf(ac2[c][2] + lb[2], 0.f), f3 = fmaxf(ac2[c][3] + lb[3], 0.f);
    float f4 = fmaxf(ac2[c][4] + lb[4], 0.f), f5 = fmaxf(ac2[c][5] + lb[5], 0.f);
    float f6 = fmaxf(ac2[c][6] + lb[6], 0.f), f7 = fmaxf(ac2[c][7] + lb[7], 0.f);
    *(float4*)&ut[wid][ng * 4 + c][jb]     = make_float4(f0, f1, f2, f3);
    *(float4*)&ut[wid][ng * 4 + c][jb + 4] = make_float4(f4, f5, f6, f7);
  }
  float ac3[4][5];
#pragma unroll
  for (int c = 0; c < 4; c++)
#pragma unroll
    for (int jj = 0; jj < 5; jj++) ac3[c][jj] = 0.f;
#pragma unroll 4
  for (int k = 0; k < 64; k++) {
    float wv[5];
#pragma unroll
    for (int jj = 0; jj < 5; jj++) wv[jj] = lh2[k * 40 + jg * 5 + jj];
    float uv[4];
#pragma unroll
    for (int c = 0; c < 4; c++) uv[c] = ut[wid][ng * 4 + c][k];
#pragma unroll
    for (int c = 0; c < 4; c++)
#pragma unroll
      for (int jj = 0; jj < 5; jj++) ac3[c][jj] = fmaf(uv[c], wv[jj], ac3[c][jj]);
  }
#pragma unroll
  for (int c = 0; c < 4; c++) {
    int n = n0 + ng * 4 + c;
#pragma unroll
    for (int jj = 0; jj < 5; jj++)
      out[(size_t)n * 40 + jg * 5 + jj] = ac3[c][jj] + l2bv[jj];
  }
}

extern "C" void kernel_launch(void* const* d_in, const int* in_sizes, int n_in,
                              void* d_out, int out_size, void* d_ws, size_t ws_size,
                              hipStream_t stream) {
  const float* x   = (const float*)d_in[0];
  const int*   ei  = (const int*)d_in[1];
  const int*   src = ei;
  const int*   dst = ei + NE;
  const float* eps = (const float*)d_in[2];
  const float* c1_w1 = (const float*)d_in[3];
  const float* c1_b1 = (const float*)d_in[4];
  const float* c1_w2 = (const float*)d_in[5];
  const float* c1_b2 = (const float*)d_in[6];
  const float* c1_gamma = (const float*)d_in[7];
  const float* c1_beta  = (const float*)d_in[8];
  const float* c1_mean  = (const float*)d_in[9];
  const float* c1_var   = (const float*)d_in[10];
  const float* cw1 = (const float*)d_in[11];
  const float* cb1 = (const float*)d_in[12];
  const float* cw2 = (const float*)d_in[13];
  const float* cb2 = (const float*)d_in[14];
  const float* cgamma = (const float*)d_in[15];
  const float* cbeta  = (const float*)d_in[16];
  const float* cmean  = (const float*)d_in[17];
  const float* cvar   = (const float*)d_in[18];
  const float* lin1_w = (const float*)d_in[19];
  const float* lin1_b = (const float*)d_in[20];
  const float* lin2_w = (const float*)d_in[21];
  const float* lin2_b = (const float*)d_in[22];
  float* out = (float*)d_out;

  char* ws = (char*)d_ws;
  int* row  = (int*)(ws + OFF_ROW);
  int* ctrl = (int*)(ws + OFF_CTRL);
  int* ch   = ctrl;          // 98
  int* coff = ctrl + 128;    // 99
  int* ccur = ctrl + 256;    // 98
  int* csr  = (int*)(ws + OFF_CSR);
  u32* pairs1 = (u32*)(ws + OFF_P1);
  float* u  = (float*)(ws + OFF_U);
  u16* yb0  = (u16*)(ws + OFF_YB0);
  u16* yb1  = (u16*)(ws + OFF_YB1);

  hipMemsetAsync(ch, 0, NCOARSE * 4, stream);

  k_hist_c<<<512, 256, 0, stream>>>(dst, ch);
  k_scan_c<<<1, 64, 0, stream>>>(ch, coff, ccur);
  k_scat1<<<(NE + SC_CH - 1) / SC_CH, 256, 0, stream>>>(src, dst, ccur, pairs1);
  k_fill3<<<NCOARSE, 256, 0, stream>>>(pairs1, coff, row, csr);

  // y0 = bf16(x @ c1_w1)
  k_gemm_x<<<2048, 256, 0, stream>>>(x, c1_w1, yb0);

  const int AGG_GRID = (NN * 8) / 256;          // 3125, exact
  const int MLP_GRID = (NN / 32 + 3) / 4;       // 782

  // layer 1
  k_agg<<<AGG_GRID, 256, 0, stream>>>(yb0, row, csr, eps, 0, c1_b1, u);
  k_mlp<<<MLP_GRID, 256, 0, stream>>>(u, c1_w2, c1_b2,
                                      c1_gamma, c1_beta, c1_mean, c1_var,
                                      cw1, yb1);
  // layer 2
  k_agg<<<AGG_GRID, 256, 0, stream>>>(yb1, row, csr, eps, 1, cb1, u);
  k_mlp<<<MLP_GRID, 256, 0, stream>>>(u, cw2, cb2,
                                      cgamma, cbeta, cmean, cvar,
                                      cw1 + 64 * 64, yb0);
  // layer 3 + head
  k_agg<<<AGG_GRID, 256, 0, stream>>>(yb0, row, csr, eps, 2, cb1 + 64, u);
  k_mlp_final<<<MLP_GRID, 256, 0, stream>>>(u, cw2 + 64 * 64, cb2 + 64,
                                            cgamma + 64, cbeta + 64, cmean + 64, cvar + 64,
                                            lin1_w, lin1_b, lin2_w, lin2_b,
                                            out);
}

// Round 5
// 322.101 us; speedup vs baseline: 9.3557x; 1.1505x over previous
//
#include <hip/hip_runtime.h>

#define NN 100000
#define NE 1600000
#define BN_EPS 1e-5f
#define NCOARSE 98   // ceil(NN/1024)
#define SC_CH 2048

typedef unsigned int u32;
typedef unsigned short u16;

// ---- workspace layout (bytes) ----
static constexpr size_t OFF_ROW  = 0;                    // (NN+1) ints
static constexpr size_t OFF_CTRL = 512u * 1024;          // ch[98], coff[99], ccur[98]
static constexpr size_t OFF_CSR  = 1u << 20;             // NE ints (6.4 MB) -> ends 7.4 MB
static constexpr size_t OFF_U    = 8u << 20;             // NN*64 f32 (25.6 MB)
static constexpr size_t OFF_P1   = OFF_U;                // alias: pairs1 dead before u live
static constexpr size_t OFF_YB0  = OFF_U + (size_t)NN * 64 * 4;   // 33,988,608
static constexpr size_t OFF_YB1  = OFF_YB0 + (size_t)NN * 64 * 2; // 46,788,608
// end = 59,588,608 bytes

__device__ __forceinline__ u16 f2bf(float f) {
  u32 u = __float_as_uint(f);
  return (u16)((u + 0x7fffu + ((u >> 16) & 1u)) >> 16);
}
__device__ __forceinline__ float bflo(u32 u) { return __uint_as_float(u << 16); }
__device__ __forceinline__ float bfhi(u32 u) { return __uint_as_float(u & 0xffff0000u); }
__device__ __forceinline__ u32 pkbf(float lo, float hi) {
  return (u32)f2bf(lo) | ((u32)f2bf(hi) << 16);
}

// ---------------- pass 1: coarse histogram ----------------
__global__ void __launch_bounds__(256) k_hist_c(const int* __restrict__ dst,
                                                int* __restrict__ ch) {
  __shared__ int h[NCOARSE];
  if (threadIdx.x < NCOARSE) h[threadIdx.x] = 0;
  __syncthreads();
  int i = blockIdx.x * 256 + threadIdx.x, stride = gridDim.x * 256;
  for (; i < NE; i += stride) atomicAdd(&h[dst[i] >> 10], 1);
  __syncthreads();
  if (threadIdx.x < NCOARSE && h[threadIdx.x]) atomicAdd(&ch[threadIdx.x], h[threadIdx.x]);
}

// ---------------- pass 2: scan 98 coarse counts ----------------
__global__ void k_scan_c(const int* __restrict__ ch, int* __restrict__ coff,
                         int* __restrict__ ccur) {
  if (threadIdx.x == 0) {
    int acc = 0;
    for (int i = 0; i < NCOARSE; i++) { coff[i] = acc; ccur[i] = acc; acc += ch[i]; }
    coff[NCOARSE] = acc;
  }
}

// ---------------- pass 3: coarse scatter ----------------
__global__ void __launch_bounds__(256) k_scat1(const int* __restrict__ src,
                                               const int* __restrict__ dst,
                                               int* __restrict__ ccur,
                                               u32* __restrict__ pairs1) {
  __shared__ int h[NCOARSE], base[NCOARSE];
  int t = threadIdx.x;
  int e0 = blockIdx.x * SC_CH;
  if (t < NCOARSE) h[t] = 0;
  __syncthreads();
  int myc[8]; u32 mypk[8];
#pragma unroll
  for (int q = 0; q < 8; q++) {
    int e = e0 + q * 256 + t;
    if (e < NE) {
      int d = dst[e], s = src[e];
      myc[q] = d >> 10;
      mypk[q] = (u32)s | ((u32)(d & 1023) << 17);
      atomicAdd(&h[myc[q]], 1);
    } else myc[q] = -1;
  }
  __syncthreads();
  if (t < NCOARSE) {
    base[t] = (h[t] > 0) ? atomicAdd(&ccur[t], h[t]) : 0;
    h[t] = 0;
  }
  __syncthreads();
#pragma unroll
  for (int q = 0; q < 8; q++) {
    if (myc[q] >= 0) {
      int p = atomicAdd(&h[myc[q]], 1);
      pairs1[base[myc[q]] + p] = mypk[q];
    }
  }
}

// ---------------- pass 4: per-bucket CSR build in LDS ----------------
__global__ void __launch_bounds__(256) k_fill3(const u32* __restrict__ pairs1,
                                               const int* __restrict__ coff,
                                               int* __restrict__ row,
                                               int* __restrict__ csr) {
  __shared__ int lcnt[1024];
  __shared__ int loff[1024];
  __shared__ int sd[256];
  __shared__ u32 stage[20480];
  int c = blockIdx.x, t = threadIdx.x;
  int es = coff[c], ee = coff[c + 1];
  int m = ee - es;
  int nbase = c << 10;
  int nodes_in = NN - nbase; if (nodes_in > 1024) nodes_in = 1024;
  for (int i = t; i < 1024; i += 256) lcnt[i] = 0;
  __syncthreads();
  for (int i = es + t; i < ee; i += 256)
    atomicAdd(&lcnt[(pairs1[i] >> 17) & 1023], 1);
  __syncthreads();
  int b4 = t * 4;
  int c0 = lcnt[b4], c1 = lcnt[b4 + 1], c2 = lcnt[b4 + 2], c3 = lcnt[b4 + 3];
  int s4 = c0 + c1 + c2 + c3;
  sd[t] = s4;
  __syncthreads();
  for (int o = 1; o < 256; o <<= 1) {
    int x = (t >= o) ? sd[t - o] : 0;
    __syncthreads();
    sd[t] += x;
    __syncthreads();
  }
  int run = sd[t] - s4;
  loff[b4] = run;     run += c0;
  loff[b4 + 1] = run; run += c1;
  loff[b4 + 2] = run; run += c2;
  loff[b4 + 3] = run;
  __syncthreads();
  for (int i = t; i < nodes_in; i += 256) row[nbase + i] = es + loff[i];
  if (c == NCOARSE - 1 && t == 0) row[NN] = NE;
  for (int i = t; i < 1024; i += 256) lcnt[i] = loff[i];
  __syncthreads();
  if (m <= 20480) {
    for (int i = es + t; i < ee; i += 256) {
      u32 pk = pairs1[i];
      int p = atomicAdd(&lcnt[(pk >> 17) & 1023], 1);
      stage[p] = pk & 0x1FFFFu;
    }
    __syncthreads();
    for (int i = t; i < m; i += 256) csr[es + i] = (int)stage[i];
  } else {
    for (int i = es + t; i < ee; i += 256) {
      u32 pk = pairs1[i];
      int p = atomicAdd(&lcnt[(pk >> 17) & 1023], 1);
      csr[es + p] = (int)(pk & 0x1FFFFu);
    }
  }
}

// ---------------- yb0 = bf16(x @ c1_w1), register-tiled (K=128) ----------------
// wave = 32-node tile; lane = (ng -> 4 nodes, jg -> 8 feats); 2 K-halves staged.
__global__ void __launch_bounds__(256) k_gemm_x(const float* __restrict__ x,
                                                const float* __restrict__ w,
                                                u16* __restrict__ yb) {
  __shared__ float lw[128 * 64];    // 32 KB, w[k][j]
  __shared__ float xt[4][32][68];   // ~34.8 KB, per-wave x tile (one K-half)
  int tid = threadIdx.x;
  for (int i = tid; i < 2048; i += 256)
    ((float4*)lw)[i] = ((const float4*)w)[i];
  int wid = tid >> 6, lane = tid & 63;
  int ng = lane >> 3, jg = lane & 7, jb = jg * 8;
  int tile = blockIdx.x * 4 + wid;
  bool act = tile < NN / 32;   // 3125 tiles, NN%32==0
  int n0 = tile * 32;
  const float* xg = x + (size_t)n0 * 128;
  float acc[4][8];
#pragma unroll
  for (int c = 0; c < 4; c++)
#pragma unroll
    for (int jj = 0; jj < 8; jj++) acc[c][jj] = 0.f;
#pragma unroll
  for (int half = 0; half < 2; half++) {
    if (act) {
#pragma unroll
      for (int p = 0; p < 8; p++) {
        int idx = p * 64 + lane;
        int r = idx >> 4, c4 = (idx & 15) * 4;
        float4 v = *(const float4*)(xg + (size_t)r * 128 + half * 64 + c4);
        *(float4*)&xt[wid][r][c4] = v;
      }
    }
    __syncthreads();
    if (act) {
      const float* lwh = lw + half * 64 * 64;
#pragma unroll 4
      for (int k = 0; k < 64; k++) {
        float4 wA = *(const float4*)&lwh[k * 64 + jb];
        float4 wB = *(const float4*)&lwh[k * 64 + jb + 4];
        float uv[4];
#pragma unroll
        for (int c = 0; c < 4; c++) uv[c] = xt[wid][ng * 4 + c][k];
#pragma unroll
        for (int c = 0; c < 4; c++) {
          acc[c][0] = fmaf(uv[c], wA.x, acc[c][0]);
          acc[c][1] = fmaf(uv[c], wA.y, acc[c][1]);
          acc[c][2] = fmaf(uv[c], wA.z, acc[c][2]);
          acc[c][3] = fmaf(uv[c], wA.w, acc[c][3]);
          acc[c][4] = fmaf(uv[c], wB.x, acc[c][4]);
          acc[c][5] = fmaf(uv[c], wB.y, acc[c][5]);
          acc[c][6] = fmaf(uv[c], wB.z, acc[c][6]);
          acc[c][7] = fmaf(uv[c], wB.w, acc[c][7]);
        }
      }
    }
    __syncthreads();
  }
  if (act) {
#pragma unroll
    for (int c = 0; c < 4; c++) {
      int n = n0 + ng * 4 + c;
      uint4 pk;
      pk.x = pkbf(acc[c][0], acc[c][1]);
      pk.y = pkbf(acc[c][2], acc[c][3]);
      pk.z = pkbf(acc[c][4], acc[c][5]);
      pk.w = pkbf(acc[c][6], acc[c][7]);
      *(uint4*)(yb + (size_t)n * 64 + jb) = pk;
    }
  }
}

// ---------------- aggregation: u = relu((1+eps)*y + sum_nbr y + b1) ----------------
__global__ void __launch_bounds__(256) k_agg(
    const u16* __restrict__ yb, const int* __restrict__ row, const int* __restrict__ csr,
    const float* __restrict__ epsv, int ei, const float* __restrict__ b1,
    float* __restrict__ u) {
  int t = blockIdx.x * 256 + threadIdx.x;
  int n = t >> 3, g = t & 7;
  if (n >= NN) return;
  const u16* bp = yb + g * 8;
  float a0 = 0, a1 = 0, a2 = 0, a3 = 0, a4 = 0, a5 = 0, a6 = 0, a7 = 0;
  int rs = row[n], re = row[n + 1];
  int i = rs;
  for (; i + 8 <= re; i += 8) {
    uint4 v[8];
#pragma unroll
    for (int q = 0; q < 8; q++) {
      int s = csr[i + q];
      v[q] = *(const uint4*)(bp + (size_t)s * 64);
    }
#pragma unroll
    for (int q = 0; q < 8; q++) {
      a0 += bflo(v[q].x); a1 += bfhi(v[q].x); a2 += bflo(v[q].y); a3 += bfhi(v[q].y);
      a4 += bflo(v[q].z); a5 += bfhi(v[q].z); a6 += bflo(v[q].w); a7 += bfhi(v[q].w);
    }
  }
  for (; i + 4 <= re; i += 4) {
    uint4 v[4];
#pragma unroll
    for (int q = 0; q < 4; q++) {
      int s = csr[i + q];
      v[q] = *(const uint4*)(bp + (size_t)s * 64);
    }
#pragma unroll
    for (int q = 0; q < 4; q++) {
      a0 += bflo(v[q].x); a1 += bfhi(v[q].x); a2 += bflo(v[q].y); a3 += bfhi(v[q].y);
      a4 += bflo(v[q].z); a5 += bfhi(v[q].z); a6 += bflo(v[q].w); a7 += bfhi(v[q].w);
    }
  }
  for (; i < re; ++i) {
    int s = csr[i];
    uint4 v0 = *(const uint4*)(bp + (size_t)s * 64);
    a0 += bflo(v0.x); a1 += bfhi(v0.x); a2 += bflo(v0.y); a3 += bfhi(v0.y);
    a4 += bflo(v0.z); a5 += bfhi(v0.z); a6 += bflo(v0.w); a7 += bfhi(v0.w);
  }
  uint4 sv = *(const uint4*)(bp + (size_t)n * 64);
  float e1 = 1.0f + epsv[ei];
  const float* bb = b1 + g * 8;
  float r0 = fmaxf(fmaf(e1, bflo(sv.x), a0 + bb[0]), 0.f);
  float r1 = fmaxf(fmaf(e1, bfhi(sv.x), a1 + bb[1]), 0.f);
  float r2 = fmaxf(fmaf(e1, bflo(sv.y), a2 + bb[2]), 0.f);
  float r3 = fmaxf(fmaf(e1, bfhi(sv.y), a3 + bb[3]), 0.f);
  float r4 = fmaxf(fmaf(e1, bflo(sv.z), a4 + bb[4]), 0.f);
  float r5 = fmaxf(fmaf(e1, bfhi(sv.z), a5 + bb[5]), 0.f);
  float r6 = fmaxf(fmaf(e1, bflo(sv.w), a6 + bb[6]), 0.f);
  float r7 = fmaxf(fmaf(e1, bfhi(sv.w), a7 + bb[7]), 0.f);
  float4* up = (float4*)(u + (size_t)n * 64 + g * 8);
  up[0] = make_float4(r0, r1, r2, r3);
  up[1] = make_float4(r4, r5, r6, r7);
}

// ---------------- MLP: yout = bf16( BN(relu(u@w2+b2)) @ wn ) ----------------
__global__ void __launch_bounds__(256) k_mlp(
    const float* __restrict__ u, const float* __restrict__ w2, const float* __restrict__ b2,
    const float* __restrict__ gamma, const float* __restrict__ beta,
    const float* __restrict__ mean, const float* __restrict__ var,
    const float* __restrict__ wn, u16* __restrict__ yout) {
  __shared__ float lw2[64 * 64];
  __shared__ float lwn[64 * 64];
  __shared__ float ut[4][32][68];
  int tid = threadIdx.x;
  for (int idx = tid; idx < 1024; idx += 256) {
    ((float4*)lw2)[idx] = ((const float4*)w2)[idx];
    ((float4*)lwn)[idx] = ((const float4*)wn)[idx];
  }
  __syncthreads();
  int wid = tid >> 6, lane = tid & 63;
  int ng = lane >> 3, jg = lane & 7;
  int jb = jg * 8;
  int tile = blockIdx.x * 4 + wid;
  if (tile >= NN / 32) return;
  float gl[8], be[8], mn[8], rv[8], bb[8];
#pragma unroll
  for (int jj = 0; jj < 8; jj++) {
    int j = jb + jj;
    gl[jj] = gamma[j]; be[jj] = beta[j]; mn[jj] = mean[j];
    rv[jj] = rsqrtf(var[j] + BN_EPS); bb[jj] = b2[j];
  }
  int n0 = tile * 32;
  int r4 = lane >> 4;
  int k0 = (lane & 15) * 4;
  const float* ug = u + (size_t)n0 * 64;
#pragma unroll
  for (int p = 0; p < 8; p++) {
    float4 val = *(const float4*)(ug + (size_t)(p * 4 + r4) * 64 + k0);
    *(float4*)&ut[wid][p * 4 + r4][k0] = val;
  }
  float acc[4][8];
#pragma unroll
  for (int c = 0; c < 4; c++)
#pragma unroll
    for (int jj = 0; jj < 8; jj++) acc[c][jj] = 0.f;
#pragma unroll 4
  for (int k = 0; k < 64; k++) {
    float4 wA = *(const float4*)&lw2[k * 64 + jb];
    float4 wB = *(const float4*)&lw2[k * 64 + jb + 4];
    float uv[4];
#pragma unroll
    for (int c = 0; c < 4; c++) uv[c] = ut[wid][ng * 4 + c][k];
#pragma unroll
    for (int c = 0; c < 4; c++) {
      acc[c][0] = fmaf(uv[c], wA.x, acc[c][0]);
      acc[c][1] = fmaf(uv[c], wA.y, acc[c][1]);
      acc[c][2] = fmaf(uv[c], wA.z, acc[c][2]);
      acc[c][3] = fmaf(uv[c], wA.w, acc[c][3]);
      acc[c][4] = fmaf(uv[c], wB.x, acc[c][4]);
      acc[c][5] = fmaf(uv[c], wB.y, acc[c][5]);
      acc[c][6] = fmaf(uv[c], wB.z, acc[c][6]);
      acc[c][7] = fmaf(uv[c], wB.w, acc[c][7]);
    }
  }
#pragma unroll
  for (int c = 0; c < 4; c++) {
    float h[8];
#pragma unroll
    for (int jj = 0; jj < 8; jj++) {
      float v = fmaxf(acc[c][jj] + bb[jj], 0.f);
      h[jj] = fmaf(gl[jj] * (v - mn[jj]), rv[jj], be[jj]);
    }
    *(float4*)&ut[wid][ng * 4 + c][jb]     = make_float4(h[0], h[1], h[2], h[3]);
    *(float4*)&ut[wid][ng * 4 + c][jb + 4] = make_float4(h[4], h[5], h[6], h[7]);
  }
  float ac2[4][8];
#pragma unroll
  for (int c = 0; c < 4; c++)
#pragma unroll
    for (int jj = 0; jj < 8; jj++) ac2[c][jj] = 0.f;
#pragma unroll 4
  for (int k = 0; k < 64; k++) {
    float4 wA = *(const float4*)&lwn[k * 64 + jb];
    float4 wB = *(const float4*)&lwn[k * 64 + jb + 4];
    float uv[4];
#pragma unroll
    for (int c = 0; c < 4; c++) uv[c] = ut[wid][ng * 4 + c][k];
#pragma unroll
    for (int c = 0; c < 4; c++) {
      ac2[c][0] = fmaf(uv[c], wA.x, ac2[c][0]);
      ac2[c][1] = fmaf(uv[c], wA.y, ac2[c][1]);
      ac2[c][2] = fmaf(uv[c], wA.z, ac2[c][2]);
      ac2[c][3] = fmaf(uv[c], wA.w, ac2[c][3]);
      ac2[c][4] = fmaf(uv[c], wB.x, ac2[c][4]);
      ac2[c][5] = fmaf(uv[c], wB.y, ac2[c][5]);
      ac2[c][6] = fmaf(uv[c], wB.z, ac2[c][6]);
      ac2[c][7] = fmaf(uv[c], wB.w, ac2[c][7]);
    }
  }
#pragma unroll
  for (int c = 0; c < 4; c++) {
    int n = n0 + ng * 4 + c;
    uint4 pk;
    pk.x = pkbf(ac2[c][0], ac2[c][1]);
    pk.y = pkbf(ac2[c][2], ac2[c][3]);
    pk.z = pkbf(ac2[c][4], ac2[c][5]);
    pk.w = pkbf(ac2[c][6], ac2[c][7]);
    *(uint4*)(yout + (size_t)n * 64 + jb) = pk;
  }
}

// ---------------- final MLP + head ----------------
__global__ void __launch_bounds__(256) k_mlp_final(
    const float* __restrict__ u, const float* __restrict__ w2, const float* __restrict__ b2,
    const float* __restrict__ gamma, const float* __restrict__ beta,
    const float* __restrict__ mean, const float* __restrict__ var,
    const float* __restrict__ l1w, const float* __restrict__ l1b,
    const float* __restrict__ l2w, const float* __restrict__ l2b,
    float* __restrict__ out) {
  __shared__ float lw2[64 * 64];
  __shared__ float lh1[64 * 64];
  __shared__ float lh2[64 * 40];
  __shared__ float ut[4][32][68];
  int tid = threadIdx.x;
  for (int idx = tid; idx < 1024; idx += 256) {
    ((float4*)lw2)[idx] = ((const float4*)w2)[idx];
    ((float4*)lh1)[idx] = ((const float4*)l1w)[idx];
  }
  for (int idx = tid; idx < 640; idx += 256) ((float4*)lh2)[idx] = ((const float4*)l2w)[idx];
  __syncthreads();
  int wid = tid >> 6, lane = tid & 63;
  int ng = lane >> 3, jg = lane & 7;
  int jb = jg * 8;
  int tile = blockIdx.x * 4 + wid;
  if (tile >= NN / 32) return;
  float gl[8], be[8], mn[8], rv[8], bb[8], lb[8];
#pragma unroll
  for (int jj = 0; jj < 8; jj++) {
    int j = jb + jj;
    gl[jj] = gamma[j]; be[jj] = beta[j]; mn[jj] = mean[j];
    rv[jj] = rsqrtf(var[j] + BN_EPS); bb[jj] = b2[j]; lb[jj] = l1b[j];
  }
  float l2bv[5];
#pragma unroll
  for (int jj = 0; jj < 5; jj++) l2bv[jj] = l2b[jg * 5 + jj];
  int n0 = tile * 32;
  int r4 = lane >> 4;
  int k0 = (lane & 15) * 4;
  const float* ug = u + (size_t)n0 * 64;
#pragma unroll
  for (int p = 0; p < 8; p++) {
    float4 val = *(const float4*)(ug + (size_t)(p * 4 + r4) * 64 + k0);
    *(float4*)&ut[wid][p * 4 + r4][k0] = val;
  }
  float acc[4][8];
#pragma unroll
  for (int c = 0; c < 4; c++)
#pragma unroll
    for (int jj = 0; jj < 8; jj++) acc[c][jj] = 0.f;
#pragma unroll 4
  for (int k = 0; k < 64; k++) {
    float4 wA = *(const float4*)&lw2[k * 64 + jb];
    float4 wB = *(const float4*)&lw2[k * 64 + jb + 4];
    float uv[4];
#pragma unroll
    for (int c = 0; c < 4; c++) uv[c] = ut[wid][ng * 4 + c][k];
#pragma unroll
    for (int c = 0; c < 4; c++) {
      acc[c][0] = fmaf(uv[c], wA.x, acc[c][0]);
      acc[c][1] = fmaf(uv[c], wA.y, acc[c][1]);
      acc[c][2] = fmaf(uv[c], wA.z, acc[c][2]);
      acc[c][3] = fmaf(uv[c], wA.w, acc[c][3]);
      acc[c][4] = fmaf(uv[c], wB.x, acc[c][4]);
      acc[c][5] = fmaf(uv[c], wB.y, acc[c][5]);
      acc[c][6] = fmaf(uv[c], wB.z, acc[c][6]);
      acc[c][7] = fmaf(uv[c], wB.w, acc[c][7]);
    }
  }
#pragma unroll
  for (int c = 0; c < 4; c++) {
    float h[8];
#pragma unroll
    for (int jj = 0; jj < 8; jj++) {
      float v = fmaxf(acc[c][jj] + bb[jj], 0.f);
      h[jj] = fmaf(gl[jj] * (v - mn[jj]), rv[jj], be[jj]);
    }
    *(float4*)&ut[wid][ng * 4 + c][jb]     = make_float4(h[0], h[1], h[2], h[3]);
    *(float4*)&ut[wid][ng * 4 + c][jb + 4] = make_float4(h[4], h[5], h[6], h[7]);
  }
  float ac2[4][8];
#pragma unroll
  for (int c = 0; c < 4; c++)
#pragma unroll
    for (int jj = 0; jj < 8; jj++) ac2[c][jj] = 0.f;
#pragma unroll 4
  for (int k = 0; k < 64; k++) {
    float4 wA = *(const float4*)&lh1[k * 64 + jb];
    float4 wB = *(const float4*)&lh1[k * 64 + jb + 4];
    float uv[4];
#pragma unroll
    for (int c = 0; c < 4; c++) uv[c] = ut[wid][ng * 4 + c][k];
#pragma unroll
    for (int c = 0; c < 4; c++) {
      ac2[c][0] = fmaf(uv[c], wA.x, ac2[c][0]);
      ac2[c][1] = fmaf(uv[c], wA.y, ac2[c][1]);
      ac2[c][2] = fmaf(uv[c], wA.z, ac2[c][2]);
      ac2[c][3] = fmaf(uv[c], wA.w, ac2[c][3]);
      ac2[c][4] = fmaf(uv[c], wB.x, ac2[c][4]);
      ac2[c][5] = fmaf(uv[c], wB.y, ac2[c][5]);
      ac2[c][6] = fmaf(uv[c], wB.z, ac2[c][6]);
      ac2[c][7] = fmaf(uv[c], wB.w, ac2[c][7]);
    }
  }
#pragma unroll
  for (int c = 0; c < 4; c++) {
    float f0 = fmaxf(ac2[c][0] + lb[0], 0.f), f1 = fmaxf(ac2[c][1] + lb[1], 0.f);
    float f2 = fmaxf(ac2[c][2] + lb[2], 0.f), f3 = fmaxf(ac2[c][3] + lb[3], 0.f);
    float f4 = fmaxf(ac2[c][4] + lb[4], 0.f), f5 = fmaxf(ac2[c][5] + lb[5], 0.f);
    float f6 = fmaxf(ac2[c][6] + lb[6], 0.f), f7 = fmaxf(ac2[c][7] + lb[7], 0.f);
    *(float4*)&ut[wid][ng * 4 + c][jb]     = make_float4(f0, f1, f2, f3);
    *(float4*)&ut[wid][ng * 4 + c][jb + 4] = make_float4(f4, f5, f6, f7);
  }
  float ac3[4][5];
#pragma unroll
  for (int c = 0; c < 4; c++)
#pragma unroll
    for (int jj = 0; jj < 5; jj++) ac3[c][jj] = 0.f;
#pragma unroll 4
  for (int k = 0; k < 64; k++) {
    float wv[5];
#pragma unroll
    for (int jj = 0; jj < 5; jj++) wv[jj] = lh2[k * 40 + jg * 5 + jj];
    float uv[4];
#pragma unroll
    for (int c = 0; c < 4; c++) uv[c] = ut[wid][ng * 4 + c][k];
#pragma unroll
    for (int c = 0; c < 4; c++)
#pragma unroll
      for (int jj = 0; jj < 5; jj++) ac3[c][jj] = fmaf(uv[c], wv[jj], ac3[c][jj]);
  }
#pragma unroll
  for (int c = 0; c < 4; c++) {
    int n = n0 + ng * 4 + c;
#pragma unroll
    for (int jj = 0; jj < 5; jj++)
      out[(size_t)n * 40 + jg * 5 + jj] = ac3[c][jj] + l2bv[jj];
  }
}

extern "C" void kernel_launch(void* const* d_in, const int* in_sizes, int n_in,
                              void* d_out, int out_size, void* d_ws, size_t ws_size,
                              hipStream_t stream) {
  const float* x   = (const float*)d_in[0];
  const int*   ei  = (const int*)d_in[1];
  const int*   src = ei;
  const int*   dst = ei + NE;
  const float* eps = (const float*)d_in[2];
  const float* c1_w1 = (const float*)d_in[3];
  const float* c1_b1 = (const float*)d_in[4];
  const float* c1_w2 = (const float*)d_in[5];
  const float* c1_b2 = (const float*)d_in[6];
  const float* c1_gamma = (const float*)d_in[7];
  const float* c1_beta  = (const float*)d_in[8];
  const float* c1_mean  = (const float*)d_in[9];
  const float* c1_var   = (const float*)d_in[10];
  const float* cw1 = (const float*)d_in[11];
  const float* cb1 = (const float*)d_in[12];
  const float* cw2 = (const float*)d_in[13];
  const float* cb2 = (const float*)d_in[14];
  const float* cgamma = (const float*)d_in[15];
  const float* cbeta  = (const float*)d_in[16];
  const float* cmean  = (const float*)d_in[17];
  const float* cvar   = (const float*)d_in[18];
  const float* lin1_w = (const float*)d_in[19];
  const float* lin1_b = (const float*)d_in[20];
  const float* lin2_w = (const float*)d_in[21];
  const float* lin2_b = (const float*)d_in[22];
  float* out = (float*)d_out;

  char* ws = (char*)d_ws;
  int* row  = (int*)(ws + OFF_ROW);
  int* ctrl = (int*)(ws + OFF_CTRL);
  int* ch   = ctrl;
  int* coff = ctrl + 128;
  int* ccur = ctrl + 256;
  int* csr  = (int*)(ws + OFF_CSR);
  u32* pairs1 = (u32*)(ws + OFF_P1);
  float* u  = (float*)(ws + OFF_U);
  u16* yb0  = (u16*)(ws + OFF_YB0);
  u16* yb1  = (u16*)(ws + OFF_YB1);

  hipMemsetAsync(ch, 0, NCOARSE * 4, stream);

  k_hist_c<<<512, 256, 0, stream>>>(dst, ch);
  k_scan_c<<<1, 64, 0, stream>>>(ch, coff, ccur);
  k_scat1<<<(NE + SC_CH - 1) / SC_CH, 256, 0, stream>>>(src, dst, ccur, pairs1);
  k_fill3<<<NCOARSE, 256, 0, stream>>>(pairs1, coff, row, csr);

  const int AGG_GRID = (NN * 8) / 256;          // 3125
  const int MLP_GRID = (NN / 32 + 3) / 4;       // 782

  // y0 = bf16(x @ c1_w1), register-tiled
  k_gemm_x<<<MLP_GRID, 256, 0, stream>>>(x, c1_w1, yb0);

  // layer 1
  k_agg<<<AGG_GRID, 256, 0, stream>>>(yb0, row, csr, eps, 0, c1_b1, u);
  k_mlp<<<MLP_GRID, 256, 0, stream>>>(u, c1_w2, c1_b2,
                                      c1_gamma, c1_beta, c1_mean, c1_var,
                                      cw1, yb1);
  // layer 2
  k_agg<<<AGG_GRID, 256, 0, stream>>>(yb1, row, csr, eps, 1, cb1, u);
  k_mlp<<<MLP_GRID, 256, 0, stream>>>(u, cw2, cb2,
                                      cgamma, cbeta, cmean, cvar,
                                      cw1 + 64 * 64, yb0);
  // layer 3 + head
  k_agg<<<AGG_GRID, 256, 0, stream>>>(yb0, row, csr, eps, 2, cb1 + 64, u);
  k_mlp_final<<<MLP_GRID, 256, 0, stream>>>(u, cw2 + 64 * 64, cb2 + 64,
                                            cgamma + 64, cbeta + 64, cmean + 64, cvar + 64,
                                            lin1_w, lin1_b, lin2_w, lin2_b,
                                            out);
}

// Round 6
// 251.583 us; speedup vs baseline: 11.9781x; 1.2803x over previous
//
#include <hip/hip_runtime.h>

#define NN 100000
#define NE 1600000
#define BN_EPS 1e-5f
#define NCOARSE 98   // ceil(NN/1024)
#define SC_CH 2048

typedef unsigned int u32;
typedef unsigned short u16;

// ---- workspace layout (bytes) ----
static constexpr size_t OFF_ROW  = 0;                    // (NN+1) ints
static constexpr size_t OFF_CTRL = 512u * 1024;          // ch[98], coff[99], ccur[98]
static constexpr size_t OFF_CSR  = 1u << 20;             // NE ints (6.4 MB)
static constexpr size_t OFF_U    = 8u << 20;             // NN*64 bf16 (12.8 MB used of 25.6 slot)
static constexpr size_t OFF_P1   = OFF_U;                // alias: pairs1 (6.4 MB) dead before ub live
static constexpr size_t OFF_YB0  = OFF_U + (size_t)NN * 64 * 4;   // 33,988,608
static constexpr size_t OFF_YB1  = OFF_YB0 + (size_t)NN * 64 * 2; // 46,788,608
// end = 59,588,608 bytes

__device__ __forceinline__ u16 f2bf(float f) {
  u32 u = __float_as_uint(f);
  return (u16)((u + 0x7fffu + ((u >> 16) & 1u)) >> 16);
}
__device__ __forceinline__ float bflo(u32 u) { return __uint_as_float(u << 16); }
__device__ __forceinline__ float bfhi(u32 u) { return __uint_as_float(u & 0xffff0000u); }
__device__ __forceinline__ u32 pkbf(float lo, float hi) {
  return (u32)f2bf(lo) | ((u32)f2bf(hi) << 16);
}

// ---- MFMA types ----
typedef __bf16 bf16x8 __attribute__((ext_vector_type(8)));
typedef float f32x4 __attribute__((ext_vector_type(4)));
union FragCvt { uint4 u; bf16x8 b; };
__device__ __forceinline__ bf16x8 frag_u16(const u16* p) {
  FragCvt c; c.u = *(const uint4*)p; return c.b;
}

// ---------------- pass 1: coarse histogram ----------------
__global__ void __launch_bounds__(256) k_hist_c(const int* __restrict__ dst,
                                                int* __restrict__ ch) {
  __shared__ int h[NCOARSE];
  if (threadIdx.x < NCOARSE) h[threadIdx.x] = 0;
  __syncthreads();
  int i = blockIdx.x * 256 + threadIdx.x, stride = gridDim.x * 256;
  for (; i < NE; i += stride) atomicAdd(&h[dst[i] >> 10], 1);
  __syncthreads();
  if (threadIdx.x < NCOARSE && h[threadIdx.x]) atomicAdd(&ch[threadIdx.x], h[threadIdx.x]);
}

// ---------------- pass 2: scan 98 coarse counts ----------------
__global__ void k_scan_c(const int* __restrict__ ch, int* __restrict__ coff,
                         int* __restrict__ ccur) {
  if (threadIdx.x == 0) {
    int acc = 0;
    for (int i = 0; i < NCOARSE; i++) { coff[i] = acc; ccur[i] = acc; acc += ch[i]; }
    coff[NCOARSE] = acc;
  }
}

// ---------------- pass 3: coarse scatter ----------------
__global__ void __launch_bounds__(256) k_scat1(const int* __restrict__ src,
                                               const int* __restrict__ dst,
                                               int* __restrict__ ccur,
                                               u32* __restrict__ pairs1) {
  __shared__ int h[NCOARSE], base[NCOARSE];
  int t = threadIdx.x;
  int e0 = blockIdx.x * SC_CH;
  if (t < NCOARSE) h[t] = 0;
  __syncthreads();
  int myc[8]; u32 mypk[8];
#pragma unroll
  for (int q = 0; q < 8; q++) {
    int e = e0 + q * 256 + t;
    if (e < NE) {
      int d = dst[e], s = src[e];
      myc[q] = d >> 10;
      mypk[q] = (u32)s | ((u32)(d & 1023) << 17);
      atomicAdd(&h[myc[q]], 1);
    } else myc[q] = -1;
  }
  __syncthreads();
  if (t < NCOARSE) {
    base[t] = (h[t] > 0) ? atomicAdd(&ccur[t], h[t]) : 0;
    h[t] = 0;
  }
  __syncthreads();
#pragma unroll
  for (int q = 0; q < 8; q++) {
    if (myc[q] >= 0) {
      int p = atomicAdd(&h[myc[q]], 1);
      pairs1[base[myc[q]] + p] = mypk[q];
    }
  }
}

// ---------------- pass 4: per-bucket CSR build in LDS ----------------
__global__ void __launch_bounds__(256) k_fill3(const u32* __restrict__ pairs1,
                                               const int* __restrict__ coff,
                                               int* __restrict__ row,
                                               int* __restrict__ csr) {
  __shared__ int lcnt[1024];
  __shared__ int loff[1024];
  __shared__ int sd[256];
  __shared__ u32 stage[20480];
  int c = blockIdx.x, t = threadIdx.x;
  int es = coff[c], ee = coff[c + 1];
  int m = ee - es;
  int nbase = c << 10;
  int nodes_in = NN - nbase; if (nodes_in > 1024) nodes_in = 1024;
  for (int i = t; i < 1024; i += 256) lcnt[i] = 0;
  __syncthreads();
  for (int i = es + t; i < ee; i += 256)
    atomicAdd(&lcnt[(pairs1[i] >> 17) & 1023], 1);
  __syncthreads();
  int b4 = t * 4;
  int c0 = lcnt[b4], c1 = lcnt[b4 + 1], c2 = lcnt[b4 + 2], c3 = lcnt[b4 + 3];
  int s4 = c0 + c1 + c2 + c3;
  sd[t] = s4;
  __syncthreads();
  for (int o = 1; o < 256; o <<= 1) {
    int x = (t >= o) ? sd[t - o] : 0;
    __syncthreads();
    sd[t] += x;
    __syncthreads();
  }
  int run = sd[t] - s4;
  loff[b4] = run;     run += c0;
  loff[b4 + 1] = run; run += c1;
  loff[b4 + 2] = run; run += c2;
  loff[b4 + 3] = run;
  __syncthreads();
  for (int i = t; i < nodes_in; i += 256) row[nbase + i] = es + loff[i];
  if (c == NCOARSE - 1 && t == 0) row[NN] = NE;
  for (int i = t; i < 1024; i += 256) lcnt[i] = loff[i];
  __syncthreads();
  if (m <= 20480) {
    for (int i = es + t; i < ee; i += 256) {
      u32 pk = pairs1[i];
      int p = atomicAdd(&lcnt[(pk >> 17) & 1023], 1);
      stage[p] = pk & 0x1FFFFu;
    }
    __syncthreads();
    for (int i = t; i < m; i += 256) csr[es + i] = (int)stage[i];
  } else {
    for (int i = es + t; i < ee; i += 256) {
      u32 pk = pairs1[i];
      int p = atomicAdd(&lcnt[(pk >> 17) & 1023], 1);
      csr[es + p] = (int)(pk & 0x1FFFFu);
    }
  }
}

// ---------------- yb0 = bf16(x @ c1_w1), register-tiled VALU (K=128) ----------------
__global__ void __launch_bounds__(256) k_gemm_x(const float* __restrict__ x,
                                                const float* __restrict__ w,
                                                u16* __restrict__ yb) {
  __shared__ float lw[128 * 64];
  __shared__ float xt[4][32][68];
  int tid = threadIdx.x;
  for (int i = tid; i < 2048; i += 256)
    ((float4*)lw)[i] = ((const float4*)w)[i];
  int wid = tid >> 6, lane = tid & 63;
  int ng = lane >> 3, jg = lane & 7, jb = jg * 8;
  int tile = blockIdx.x * 4 + wid;
  bool act = tile < NN / 32;
  int n0 = tile * 32;
  const float* xg = x + (size_t)n0 * 128;
  float acc[4][8];
#pragma unroll
  for (int c = 0; c < 4; c++)
#pragma unroll
    for (int jj = 0; jj < 8; jj++) acc[c][jj] = 0.f;
#pragma unroll
  for (int half = 0; half < 2; half++) {
    if (act) {
#pragma unroll
      for (int p = 0; p < 8; p++) {
        int idx = p * 64 + lane;
        int r = idx >> 4, c4 = (idx & 15) * 4;
        float4 v = *(const float4*)(xg + (size_t)r * 128 + half * 64 + c4);
        *(float4*)&xt[wid][r][c4] = v;
      }
    }
    __syncthreads();
    if (act) {
      const float* lwh = lw + half * 64 * 64;
#pragma unroll 4
      for (int k = 0; k < 64; k++) {
        float4 wA = *(const float4*)&lwh[k * 64 + jb];
        float4 wB = *(const float4*)&lwh[k * 64 + jb + 4];
        float uv[4];
#pragma unroll
        for (int c = 0; c < 4; c++) uv[c] = xt[wid][ng * 4 + c][k];
#pragma unroll
        for (int c = 0; c < 4; c++) {
          acc[c][0] = fmaf(uv[c], wA.x, acc[c][0]);
          acc[c][1] = fmaf(uv[c], wA.y, acc[c][1]);
          acc[c][2] = fmaf(uv[c], wA.z, acc[c][2]);
          acc[c][3] = fmaf(uv[c], wA.w, acc[c][3]);
          acc[c][4] = fmaf(uv[c], wB.x, acc[c][4]);
          acc[c][5] = fmaf(uv[c], wB.y, acc[c][5]);
          acc[c][6] = fmaf(uv[c], wB.z, acc[c][6]);
          acc[c][7] = fmaf(uv[c], wB.w, acc[c][7]);
        }
      }
    }
    __syncthreads();
  }
  if (act) {
#pragma unroll
    for (int c = 0; c < 4; c++) {
      int n = n0 + ng * 4 + c;
      uint4 pk;
      pk.x = pkbf(acc[c][0], acc[c][1]);
      pk.y = pkbf(acc[c][2], acc[c][3]);
      pk.z = pkbf(acc[c][4], acc[c][5]);
      pk.w = pkbf(acc[c][6], acc[c][7]);
      *(uint4*)(yb + (size_t)n * 64 + jb) = pk;
    }
  }
}

// ---------------- aggregation: ub = bf16(relu((1+eps)*y + sum_nbr y + b1)) ----------------
__global__ void __launch_bounds__(256) k_agg(
    const u16* __restrict__ yb, const int* __restrict__ row, const int* __restrict__ csr,
    const float* __restrict__ epsv, int ei, const float* __restrict__ b1,
    u16* __restrict__ ub) {
  int t = blockIdx.x * 256 + threadIdx.x;
  int n = t >> 3, g = t & 7;
  if (n >= NN) return;
  const u16* bp = yb + g * 8;
  float a0 = 0, a1 = 0, a2 = 0, a3 = 0, a4 = 0, a5 = 0, a6 = 0, a7 = 0;
  int rs = row[n], re = row[n + 1];
  int i = rs;
  for (; i + 8 <= re; i += 8) {
    uint4 v[8];
#pragma unroll
    for (int q = 0; q < 8; q++) {
      int s = csr[i + q];
      v[q] = *(const uint4*)(bp + (size_t)s * 64);
    }
#pragma unroll
    for (int q = 0; q < 8; q++) {
      a0 += bflo(v[q].x); a1 += bfhi(v[q].x); a2 += bflo(v[q].y); a3 += bfhi(v[q].y);
      a4 += bflo(v[q].z); a5 += bfhi(v[q].z); a6 += bflo(v[q].w); a7 += bfhi(v[q].w);
    }
  }
  for (; i + 4 <= re; i += 4) {
    uint4 v[4];
#pragma unroll
    for (int q = 0; q < 4; q++) {
      int s = csr[i + q];
      v[q] = *(const uint4*)(bp + (size_t)s * 64);
    }
#pragma unroll
    for (int q = 0; q < 4; q++) {
      a0 += bflo(v[q].x); a1 += bfhi(v[q].x); a2 += bflo(v[q].y); a3 += bfhi(v[q].y);
      a4 += bflo(v[q].z); a5 += bfhi(v[q].z); a6 += bflo(v[q].w); a7 += bfhi(v[q].w);
    }
  }
  for (; i < re; ++i) {
    int s = csr[i];
    uint4 v0 = *(const uint4*)(bp + (size_t)s * 64);
    a0 += bflo(v0.x); a1 += bfhi(v0.x); a2 += bflo(v0.y); a3 += bfhi(v0.y);
    a4 += bflo(v0.z); a5 += bfhi(v0.z); a6 += bflo(v0.w); a7 += bfhi(v0.w);
  }
  uint4 sv = *(const uint4*)(bp + (size_t)n * 64);
  float e1 = 1.0f + epsv[ei];
  const float* bb = b1 + g * 8;
  float r0 = fmaxf(fmaf(e1, bflo(sv.x), a0 + bb[0]), 0.f);
  float r1 = fmaxf(fmaf(e1, bfhi(sv.x), a1 + bb[1]), 0.f);
  float r2 = fmaxf(fmaf(e1, bflo(sv.y), a2 + bb[2]), 0.f);
  float r3 = fmaxf(fmaf(e1, bfhi(sv.y), a3 + bb[3]), 0.f);
  float r4 = fmaxf(fmaf(e1, bflo(sv.z), a4 + bb[4]), 0.f);
  float r5 = fmaxf(fmaf(e1, bfhi(sv.z), a5 + bb[5]), 0.f);
  float r6 = fmaxf(fmaf(e1, bflo(sv.w), a6 + bb[6]), 0.f);
  float r7 = fmaxf(fmaf(e1, bfhi(sv.w), a7 + bb[7]), 0.f);
  uint4 pk;
  pk.x = pkbf(r0, r1); pk.y = pkbf(r2, r3);
  pk.z = pkbf(r4, r5); pk.w = pkbf(r6, r7);
  *(uint4*)(ub + (size_t)n * 64 + g * 8) = pk;
}

// ---------------- MFMA MLP: yout = bf16( BN(relu(ub@w2+b2)) @ wn ) ----------------
// wave = 32 nodes; mfma_f32_16x16x32_bf16; A row=lane&15, k=(lane>>4)*8+i;
// C/D col=lane&15, row=(lane>>4)*4+r  [guide §3, m89-verified]
__global__ void __launch_bounds__(256) k_mlp_mfma(
    const u16* __restrict__ ub, const float* __restrict__ w2, const float* __restrict__ b2,
    const float* __restrict__ gamma, const float* __restrict__ beta,
    const float* __restrict__ mean, const float* __restrict__ var,
    const float* __restrict__ wn, u16* __restrict__ yout) {
  __shared__ __align__(16) u16 w2T[64][72];   // wT[n][k] bf16
  __shared__ __align__(16) u16 wnT[64][72];
  __shared__ __align__(16) u16 ht[4][32][72]; // per-wave transpose tile
  int tid = threadIdx.x;
  for (int idx = tid; idx < 4096; idx += 256) {
    int k = idx >> 6, n = idx & 63;
    w2T[n][k] = f2bf(w2[idx]);
    wnT[n][k] = f2bf(wn[idx]);
  }
  __syncthreads();
  int wid = tid >> 6, lane = tid & 63;
  int grp = blockIdx.x * 4 + wid;
  if (grp >= NN / 32) return;
  int g0 = grp * 32;
  int mrow = lane & 15;
  int kc8 = (lane >> 4) * 8;
  int q4 = (lane >> 4) * 4;
  // BN/bias params per n-tile
  float bb[4], gl[4], be[4], mn[4], rv[4];
#pragma unroll
  for (int nt = 0; nt < 4; nt++) {
    int j = nt * 16 + mrow;
    bb[nt] = b2[j]; gl[nt] = gamma[j]; be[nt] = beta[j]; mn[nt] = mean[j];
    rv[nt] = rsqrtf(var[j] + BN_EPS);
  }
  // A-frags from global ub
  bf16x8 a[2][2];
#pragma unroll
  for (int mt = 0; mt < 2; mt++)
#pragma unroll
    for (int kc = 0; kc < 2; kc++)
      a[mt][kc] = frag_u16(ub + (size_t)(g0 + mt * 16 + mrow) * 64 + kc * 32 + kc8);
  f32x4 zero = {0.f, 0.f, 0.f, 0.f};
  // gemm1
  f32x4 acc[2][4];
#pragma unroll
  for (int nt = 0; nt < 4; nt++) {
    bf16x8 b0 = frag_u16(&w2T[nt * 16 + mrow][kc8]);
    bf16x8 b1f = frag_u16(&w2T[nt * 16 + mrow][32 + kc8]);
#pragma unroll
    for (int mt = 0; mt < 2; mt++) {
      acc[mt][nt] = __builtin_amdgcn_mfma_f32_16x16x32_bf16(a[mt][0], b0, zero, 0, 0, 0);
      acc[mt][nt] = __builtin_amdgcn_mfma_f32_16x16x32_bf16(a[mt][1], b1f, acc[mt][nt], 0, 0, 0);
    }
  }
  // epilogue1: bias+relu+BN -> ht (bf16)
#pragma unroll
  for (int mt = 0; mt < 2; mt++)
#pragma unroll
    for (int nt = 0; nt < 4; nt++)
#pragma unroll
      for (int r = 0; r < 4; r++) {
        float v = fmaxf(acc[mt][nt][r] + bb[nt], 0.f);
        float h = fmaf(gl[nt] * (v - mn[nt]), rv[nt], be[nt]);
        ht[wid][mt * 16 + q4 + r][nt * 16 + mrow] = f2bf(h);
      }
  asm volatile("s_waitcnt lgkmcnt(0)" ::: "memory");
  // gemm2
  bf16x8 a2[2][2];
#pragma unroll
  for (int mt = 0; mt < 2; mt++)
#pragma unroll
    for (int kc = 0; kc < 2; kc++)
      a2[mt][kc] = frag_u16(&ht[wid][mt * 16 + mrow][kc * 32 + kc8]);
  f32x4 ac2[2][4];
#pragma unroll
  for (int nt = 0; nt < 4; nt++) {
    bf16x8 b0 = frag_u16(&wnT[nt * 16 + mrow][kc8]);
    bf16x8 b1f = frag_u16(&wnT[nt * 16 + mrow][32 + kc8]);
#pragma unroll
    for (int mt = 0; mt < 2; mt++) {
      ac2[mt][nt] = __builtin_amdgcn_mfma_f32_16x16x32_bf16(a2[mt][0], b0, zero, 0, 0, 0);
      ac2[mt][nt] = __builtin_amdgcn_mfma_f32_16x16x32_bf16(a2[mt][1], b1f, ac2[mt][nt], 0, 0, 0);
    }
  }
  asm volatile("s_waitcnt lgkmcnt(0)" ::: "memory");
  // epilogue2: pack to ht then coalesced store
#pragma unroll
  for (int mt = 0; mt < 2; mt++)
#pragma unroll
    for (int nt = 0; nt < 4; nt++)
#pragma unroll
      for (int r = 0; r < 4; r++)
        ht[wid][mt * 16 + q4 + r][nt * 16 + mrow] = f2bf(ac2[mt][nt][r]);
  asm volatile("s_waitcnt lgkmcnt(0)" ::: "memory");
#pragma unroll
  for (int it = 0; it < 4; it++) {
    int idx = it * 64 + lane;
    int rw = idx >> 3, ch = idx & 7;
    uint4 v = *(const uint4*)&ht[wid][rw][ch * 8];
    *(uint4*)(yout + (size_t)(g0 + rw) * 64 + ch * 8) = v;
  }
}

// ---------------- MFMA final MLP + head ----------------
__global__ void __launch_bounds__(256) k_mlp_final_mfma(
    const u16* __restrict__ ub, const float* __restrict__ w2, const float* __restrict__ b2,
    const float* __restrict__ gamma, const float* __restrict__ beta,
    const float* __restrict__ mean, const float* __restrict__ var,
    const float* __restrict__ l1w, const float* __restrict__ l1b,
    const float* __restrict__ l2w, const float* __restrict__ l2b,
    float* __restrict__ out) {
  __shared__ __align__(16) u16 w2T[64][72];
  __shared__ __align__(16) u16 l1T[64][72];
  __shared__ __align__(16) u16 l2T[48][72];
  __shared__ __align__(16) u16 ht[4][32][72];
  int tid = threadIdx.x;
  for (int idx = tid; idx < 4096; idx += 256) {
    int k = idx >> 6, n = idx & 63;
    w2T[n][k] = f2bf(w2[idx]);
    l1T[n][k] = f2bf(l1w[idx]);
  }
  for (int idx = tid; idx < 3072; idx += 256) {
    int n = idx >> 6, k = idx & 63;
    l2T[n][k] = f2bf((n < 40) ? l2w[k * 40 + n] : 0.f);
  }
  __syncthreads();
  int wid = tid >> 6, lane = tid & 63;
  int grp = blockIdx.x * 4 + wid;
  if (grp >= NN / 32) return;
  int g0 = grp * 32;
  int mrow = lane & 15;
  int kc8 = (lane >> 4) * 8;
  int q4 = (lane >> 4) * 4;
  float bb[4], gl[4], be[4], mn[4], rv[4], l1bv[4];
#pragma unroll
  for (int nt = 0; nt < 4; nt++) {
    int j = nt * 16 + mrow;
    bb[nt] = b2[j]; gl[nt] = gamma[j]; be[nt] = beta[j]; mn[nt] = mean[j];
    rv[nt] = rsqrtf(var[j] + BN_EPS); l1bv[nt] = l1b[j];
  }
  float l2bv[3];
#pragma unroll
  for (int nt = 0; nt < 3; nt++) {
    int j = nt * 16 + mrow;
    l2bv[nt] = (j < 40) ? l2b[j] : 0.f;
  }
  bf16x8 a[2][2];
#pragma unroll
  for (int mt = 0; mt < 2; mt++)
#pragma unroll
    for (int kc = 0; kc < 2; kc++)
      a[mt][kc] = frag_u16(ub + (size_t)(g0 + mt * 16 + mrow) * 64 + kc * 32 + kc8);
  f32x4 zero = {0.f, 0.f, 0.f, 0.f};
  // gemm1: u@w2 -> BN -> ht
  f32x4 acc[2][4];
#pragma unroll
  for (int nt = 0; nt < 4; nt++) {
    bf16x8 b0 = frag_u16(&w2T[nt * 16 + mrow][kc8]);
    bf16x8 b1f = frag_u16(&w2T[nt * 16 + mrow][32 + kc8]);
#pragma unroll
    for (int mt = 0; mt < 2; mt++) {
      acc[mt][nt] = __builtin_amdgcn_mfma_f32_16x16x32_bf16(a[mt][0], b0, zero, 0, 0, 0);
      acc[mt][nt] = __builtin_amdgcn_mfma_f32_16x16x32_bf16(a[mt][1], b1f, acc[mt][nt], 0, 0, 0);
    }
  }
#pragma unroll
  for (int mt = 0; mt < 2; mt++)
#pragma unroll
    for (int nt = 0; nt < 4; nt++)
#pragma unroll
      for (int r = 0; r < 4; r++) {
        float v = fmaxf(acc[mt][nt][r] + bb[nt], 0.f);
        float h = fmaf(gl[nt] * (v - mn[nt]), rv[nt], be[nt]);
        ht[wid][mt * 16 + q4 + r][nt * 16 + mrow] = f2bf(h);
      }
  asm volatile("s_waitcnt lgkmcnt(0)" ::: "memory");
  // gemm2: h@l1w -> relu -> ht
  bf16x8 a2[2][2];
#pragma unroll
  for (int mt = 0; mt < 2; mt++)
#pragma unroll
    for (int kc = 0; kc < 2; kc++)
      a2[mt][kc] = frag_u16(&ht[wid][mt * 16 + mrow][kc * 32 + kc8]);
  f32x4 ac2[2][4];
#pragma unroll
  for (int nt = 0; nt < 4; nt++) {
    bf16x8 b0 = frag_u16(&l1T[nt * 16 + mrow][kc8]);
    bf16x8 b1f = frag_u16(&l1T[nt * 16 + mrow][32 + kc8]);
#pragma unroll
    for (int mt = 0; mt < 2; mt++) {
      ac2[mt][nt] = __builtin_amdgcn_mfma_f32_16x16x32_bf16(a2[mt][0], b0, zero, 0, 0, 0);
      ac2[mt][nt] = __builtin_amdgcn_mfma_f32_16x16x32_bf16(a2[mt][1], b1f, ac2[mt][nt], 0, 0, 0);
    }
  }
  asm volatile("s_waitcnt lgkmcnt(0)" ::: "memory");
#pragma unroll
  for (int mt = 0; mt < 2; mt++)
#pragma unroll
    for (int nt = 0; nt < 4; nt++)
#pragma unroll
      for (int r = 0; r < 4; r++) {
        float f = fmaxf(ac2[mt][nt][r] + l1bv[nt], 0.f);
        ht[wid][mt * 16 + q4 + r][nt * 16 + mrow] = f2bf(f);
      }
  asm volatile("s_waitcnt lgkmcnt(0)" ::: "memory");
  // gemm3: f@l2w (N=48, valid 40)
  bf16x8 a3[2][2];
#pragma unroll
  for (int mt = 0; mt < 2; mt++)
#pragma unroll
    for (int kc = 0; kc < 2; kc++)
      a3[mt][kc] = frag_u16(&ht[wid][mt * 16 + mrow][kc * 32 + kc8]);
  f32x4 ac3[2][3];
#pragma unroll
  for (int nt = 0; nt < 3; nt++) {
    bf16x8 b0 = frag_u16(&l2T[nt * 16 + mrow][kc8]);
    bf16x8 b1f = frag_u16(&l2T[nt * 16 + mrow][32 + kc8]);
#pragma unroll
    for (int mt = 0; mt < 2; mt++) {
      ac3[mt][nt] = __builtin_amdgcn_mfma_f32_16x16x32_bf16(a3[mt][0], b0, zero, 0, 0, 0);
      ac3[mt][nt] = __builtin_amdgcn_mfma_f32_16x16x32_bf16(a3[mt][1], b1f, ac3[mt][nt], 0, 0, 0);
    }
  }
#pragma unroll
  for (int mt = 0; mt < 2; mt++)
#pragma unroll
    for (int nt = 0; nt < 3; nt++) {
      int j = nt * 16 + mrow;
      if (j < 40) {
#pragma unroll
        for (int r = 0; r < 4; r++)
          out[(size_t)(g0 + mt * 16 + q4 + r) * 40 + j] = ac3[mt][nt][r] + l2bv[nt];
      }
    }
}

extern "C" void kernel_launch(void* const* d_in, const int* in_sizes, int n_in,
                              void* d_out, int out_size, void* d_ws, size_t ws_size,
                              hipStream_t stream) {
  const float* x   = (const float*)d_in[0];
  const int*   ei  = (const int*)d_in[1];
  const int*   src = ei;
  const int*   dst = ei + NE;
  const float* eps = (const float*)d_in[2];
  const float* c1_w1 = (const float*)d_in[3];
  const float* c1_b1 = (const float*)d_in[4];
  const float* c1_w2 = (const float*)d_in[5];
  const float* c1_b2 = (const float*)d_in[6];
  const float* c1_gamma = (const float*)d_in[7];
  const float* c1_beta  = (const float*)d_in[8];
  const float* c1_mean  = (const float*)d_in[9];
  const float* c1_var   = (const float*)d_in[10];
  const float* cw1 = (const float*)d_in[11];
  const float* cb1 = (const float*)d_in[12];
  const float* cw2 = (const float*)d_in[13];
  const float* cb2 = (const float*)d_in[14];
  const float* cgamma = (const float*)d_in[15];
  const float* cbeta  = (const float*)d_in[16];
  const float* cmean  = (const float*)d_in[17];
  const float* cvar   = (const float*)d_in[18];
  const float* lin1_w = (const float*)d_in[19];
  const float* lin1_b = (const float*)d_in[20];
  const float* lin2_w = (const float*)d_in[21];
  const float* lin2_b = (const float*)d_in[22];
  float* out = (float*)d_out;

  char* ws = (char*)d_ws;
  int* row  = (int*)(ws + OFF_ROW);
  int* ctrl = (int*)(ws + OFF_CTRL);
  int* ch   = ctrl;
  int* coff = ctrl + 128;
  int* ccur = ctrl + 256;
  int* csr  = (int*)(ws + OFF_CSR);
  u32* pairs1 = (u32*)(ws + OFF_P1);
  u16* ubuf = (u16*)(ws + OFF_U);
  u16* yb0  = (u16*)(ws + OFF_YB0);
  u16* yb1  = (u16*)(ws + OFF_YB1);

  hipMemsetAsync(ch, 0, NCOARSE * 4, stream);

  k_hist_c<<<512, 256, 0, stream>>>(dst, ch);
  k_scan_c<<<1, 64, 0, stream>>>(ch, coff, ccur);
  k_scat1<<<(NE + SC_CH - 1) / SC_CH, 256, 0, stream>>>(src, dst, ccur, pairs1);
  k_fill3<<<NCOARSE, 256, 0, stream>>>(pairs1, coff, row, csr);

  const int AGG_GRID = (NN * 8) / 256;          // 3125
  const int MLP_GRID = (NN / 32 + 3) / 4;       // 782

  // y0 = bf16(x @ c1_w1)
  k_gemm_x<<<MLP_GRID, 256, 0, stream>>>(x, c1_w1, yb0);

  // layer 1
  k_agg<<<AGG_GRID, 256, 0, stream>>>(yb0, row, csr, eps, 0, c1_b1, ubuf);
  k_mlp_mfma<<<MLP_GRID, 256, 0, stream>>>(ubuf, c1_w2, c1_b2,
                                           c1_gamma, c1_beta, c1_mean, c1_var,
                                           cw1, yb1);
  // layer 2
  k_agg<<<AGG_GRID, 256, 0, stream>>>(yb1, row, csr, eps, 1, cb1, ubuf);
  k_mlp_mfma<<<MLP_GRID, 256, 0, stream>>>(ubuf, cw2, cb2,
                                           cgamma, cbeta, cmean, cvar,
                                           cw1 + 64 * 64, yb0);
  // layer 3 + head
  k_agg<<<AGG_GRID, 256, 0, stream>>>(yb0, row, csr, eps, 2, cb1 + 64, ubuf);
  k_mlp_final_mfma<<<MLP_GRID, 256, 0, stream>>>(ubuf, cw2 + 64 * 64, cb2 + 64,
                                                 cgamma + 64, cbeta + 64, cmean + 64, cvar + 64,
                                                 lin1_w, lin1_b, lin2_w, lin2_b,
                                                 out);
}

// Round 7
// 233.506 us; speedup vs baseline: 12.9054x; 1.0774x over previous
//
#include <hip/hip_runtime.h>

#define NN 100000
#define NE 1600000
#define BN_EPS 1e-5f
#define NCOARSE 98   // ceil(NN/1024)
#define SC_CH 2048

typedef unsigned int u32;
typedef unsigned short u16;

// ---- workspace layout (bytes) ----
static constexpr size_t OFF_ROW  = 0;                    // (NN+1) ints
static constexpr size_t OFF_CTRL = 512u * 1024;          // ch[98], coff[99], ccur[98]
static constexpr size_t OFF_CSR  = 1u << 20;             // NE ints (6.4 MB)
static constexpr size_t OFF_U    = 8u << 20;             // NN*64 bf16
static constexpr size_t OFF_P1   = OFF_U;                // alias: pairs1 dead before ub live
static constexpr size_t OFF_YB0  = OFF_U + (size_t)NN * 64 * 4;   // 33,988,608
static constexpr size_t OFF_YB1  = OFF_YB0 + (size_t)NN * 64 * 2; // 46,788,608
// end = 59,588,608 bytes

__device__ __forceinline__ u16 f2bf(float f) {
  u32 u = __float_as_uint(f);
  return (u16)((u + 0x7fffu + ((u >> 16) & 1u)) >> 16);
}
__device__ __forceinline__ float bflo(u32 u) { return __uint_as_float(u << 16); }
__device__ __forceinline__ float bfhi(u32 u) { return __uint_as_float(u & 0xffff0000u); }
__device__ __forceinline__ u32 pkbf(float lo, float hi) {
  return (u32)f2bf(lo) | ((u32)f2bf(hi) << 16);
}

// ---- MFMA types ----
typedef __bf16 bf16x8 __attribute__((ext_vector_type(8)));
typedef float f32x4 __attribute__((ext_vector_type(4)));
union FragCvt { uint4 u; bf16x8 b; u16 s[8]; };
__device__ __forceinline__ bf16x8 frag_u16(const u16* p) {
  FragCvt c; c.u = *(const uint4*)p; return c.b;
}

// ---------------- pass 1: coarse histogram ----------------
__global__ void __launch_bounds__(256) k_hist_c(const int* __restrict__ dst,
                                                int* __restrict__ ch) {
  __shared__ int h[NCOARSE];
  if (threadIdx.x < NCOARSE) h[threadIdx.x] = 0;
  __syncthreads();
  int i = blockIdx.x * 256 + threadIdx.x, stride = gridDim.x * 256;
  for (; i < NE; i += stride) atomicAdd(&h[dst[i] >> 10], 1);
  __syncthreads();
  if (threadIdx.x < NCOARSE && h[threadIdx.x]) atomicAdd(&ch[threadIdx.x], h[threadIdx.x]);
}

// ---------------- pass 2: scan 98 coarse counts ----------------
__global__ void k_scan_c(const int* __restrict__ ch, int* __restrict__ coff,
                         int* __restrict__ ccur) {
  if (threadIdx.x == 0) {
    int acc = 0;
    for (int i = 0; i < NCOARSE; i++) { coff[i] = acc; ccur[i] = acc; acc += ch[i]; }
    coff[NCOARSE] = acc;
  }
}

// ---------------- pass 3: coarse scatter ----------------
__global__ void __launch_bounds__(256) k_scat1(const int* __restrict__ src,
                                               const int* __restrict__ dst,
                                               int* __restrict__ ccur,
                                               u32* __restrict__ pairs1) {
  __shared__ int h[NCOARSE], base[NCOARSE];
  int t = threadIdx.x;
  int e0 = blockIdx.x * SC_CH;
  if (t < NCOARSE) h[t] = 0;
  __syncthreads();
  int myc[8]; u32 mypk[8];
#pragma unroll
  for (int q = 0; q < 8; q++) {
    int e = e0 + q * 256 + t;
    if (e < NE) {
      int d = dst[e], s = src[e];
      myc[q] = d >> 10;
      mypk[q] = (u32)s | ((u32)(d & 1023) << 17);
      atomicAdd(&h[myc[q]], 1);
    } else myc[q] = -1;
  }
  __syncthreads();
  if (t < NCOARSE) {
    base[t] = (h[t] > 0) ? atomicAdd(&ccur[t], h[t]) : 0;
    h[t] = 0;
  }
  __syncthreads();
#pragma unroll
  for (int q = 0; q < 8; q++) {
    if (myc[q] >= 0) {
      int p = atomicAdd(&h[myc[q]], 1);
      pairs1[base[myc[q]] + p] = mypk[q];
    }
  }
}

// ---------------- pass 4: per-bucket CSR build in LDS ----------------
__global__ void __launch_bounds__(256) k_fill3(const u32* __restrict__ pairs1,
                                               const int* __restrict__ coff,
                                               int* __restrict__ row,
                                               int* __restrict__ csr) {
  __shared__ int lcnt[1024];
  __shared__ int loff[1024];
  __shared__ int sd[256];
  __shared__ u32 stage[20480];
  int c = blockIdx.x, t = threadIdx.x;
  int es = coff[c], ee = coff[c + 1];
  int m = ee - es;
  int nbase = c << 10;
  int nodes_in = NN - nbase; if (nodes_in > 1024) nodes_in = 1024;
  for (int i = t; i < 1024; i += 256) lcnt[i] = 0;
  __syncthreads();
  for (int i = es + t; i < ee; i += 256)
    atomicAdd(&lcnt[(pairs1[i] >> 17) & 1023], 1);
  __syncthreads();
  int b4 = t * 4;
  int c0 = lcnt[b4], c1 = lcnt[b4 + 1], c2 = lcnt[b4 + 2], c3 = lcnt[b4 + 3];
  int s4 = c0 + c1 + c2 + c3;
  sd[t] = s4;
  __syncthreads();
  for (int o = 1; o < 256; o <<= 1) {
    int x = (t >= o) ? sd[t - o] : 0;
    __syncthreads();
    sd[t] += x;
    __syncthreads();
  }
  int run = sd[t] - s4;
  loff[b4] = run;     run += c0;
  loff[b4 + 1] = run; run += c1;
  loff[b4 + 2] = run; run += c2;
  loff[b4 + 3] = run;
  __syncthreads();
  for (int i = t; i < nodes_in; i += 256) row[nbase + i] = es + loff[i];
  if (c == NCOARSE - 1 && t == 0) row[NN] = NE;
  for (int i = t; i < 1024; i += 256) lcnt[i] = loff[i];
  __syncthreads();
  if (m <= 20480) {
    for (int i = es + t; i < ee; i += 256) {
      u32 pk = pairs1[i];
      int p = atomicAdd(&lcnt[(pk >> 17) & 1023], 1);
      stage[p] = pk & 0x1FFFFu;
    }
    __syncthreads();
    for (int i = t; i < m; i += 256) csr[es + i] = (int)stage[i];
  } else {
    for (int i = es + t; i < ee; i += 256) {
      u32 pk = pairs1[i];
      int p = atomicAdd(&lcnt[(pk >> 17) & 1023], 1);
      csr[es + p] = (int)(pk & 0x1FFFFu);
    }
  }
}

// ---------------- yb0 = bf16(x @ c1_w1), MFMA (K=128) ----------------
// wave = 32 nodes; A-frags from global fp32 x (converted); B = w1 bf16 in LDS.
__global__ void __launch_bounds__(256) k_gemm_x_mfma(const float* __restrict__ x,
                                                     const float* __restrict__ w,
                                                     u16* __restrict__ yb) {
  __shared__ __align__(16) u16 wT[64][136];   // [n][k], 17.4 KB
  __shared__ __align__(16) u16 ht[4][32][72]; // 18.4 KB
  int tid = threadIdx.x;
  for (int idx = tid; idx < 8192; idx += 256) {
    int k = idx >> 6, n = idx & 63;
    wT[n][k] = f2bf(w[idx]);
  }
  __syncthreads();
  int wid = tid >> 6, lane = tid & 63;
  int grp = blockIdx.x * 4 + wid;
  if (grp >= NN / 32) return;   // no barriers after this point
  int g0 = grp * 32;
  int mrow = lane & 15;
  int kc8 = (lane >> 4) * 8;
  int q4 = (lane >> 4) * 4;
  // A-frags: x rows -> bf16, layout row=lane&15, k=kc*32+(lane>>4)*8+i
  bf16x8 a[2][4];
#pragma unroll
  for (int mt = 0; mt < 2; mt++) {
    const float* xr = x + (size_t)(g0 + mt * 16 + mrow) * 128;
#pragma unroll
    for (int kc = 0; kc < 4; kc++) {
      float4 v0 = *(const float4*)(xr + kc * 32 + kc8);
      float4 v1 = *(const float4*)(xr + kc * 32 + kc8 + 4);
      FragCvt fc;
      fc.s[0] = f2bf(v0.x); fc.s[1] = f2bf(v0.y); fc.s[2] = f2bf(v0.z); fc.s[3] = f2bf(v0.w);
      fc.s[4] = f2bf(v1.x); fc.s[5] = f2bf(v1.y); fc.s[6] = f2bf(v1.z); fc.s[7] = f2bf(v1.w);
      a[mt][kc] = fc.b;
    }
  }
  f32x4 zero = {0.f, 0.f, 0.f, 0.f};
  f32x4 acc[2][4];
#pragma unroll
  for (int nt = 0; nt < 4; nt++) {
    bf16x8 bf[4];
#pragma unroll
    for (int kc = 0; kc < 4; kc++)
      bf[kc] = frag_u16(&wT[nt * 16 + mrow][kc * 32 + kc8]);
#pragma unroll
    for (int mt = 0; mt < 2; mt++) {
      f32x4 c = __builtin_amdgcn_mfma_f32_16x16x32_bf16(a[mt][0], bf[0], zero, 0, 0, 0);
      c = __builtin_amdgcn_mfma_f32_16x16x32_bf16(a[mt][1], bf[1], c, 0, 0, 0);
      c = __builtin_amdgcn_mfma_f32_16x16x32_bf16(a[mt][2], bf[2], c, 0, 0, 0);
      c = __builtin_amdgcn_mfma_f32_16x16x32_bf16(a[mt][3], bf[3], c, 0, 0, 0);
      acc[mt][nt] = c;
    }
  }
  // transpose-pack via per-wave ht tile, then coalesced store
#pragma unroll
  for (int mt = 0; mt < 2; mt++)
#pragma unroll
    for (int nt = 0; nt < 4; nt++)
#pragma unroll
      for (int r = 0; r < 4; r++)
        ht[wid][mt * 16 + q4 + r][nt * 16 + mrow] = f2bf(acc[mt][nt][r]);
  asm volatile("s_waitcnt lgkmcnt(0)" ::: "memory");
#pragma unroll
  for (int it = 0; it < 4; it++) {
    int idx = it * 64 + lane;
    int rw = idx >> 3, ch = idx & 7;
    uint4 v = *(const uint4*)&ht[wid][rw][ch * 8];
    *(uint4*)(yb + (size_t)(g0 + rw) * 64 + ch * 8) = v;
  }
}

// ---------------- aggregation: ub = bf16(relu((1+eps)*y + sum_nbr y + b1)) ----------------
__global__ void __launch_bounds__(256) k_agg(
    const u16* __restrict__ yb, const int* __restrict__ row, const int* __restrict__ csr,
    const float* __restrict__ epsv, int ei, const float* __restrict__ b1,
    u16* __restrict__ ub) {
  int t = blockIdx.x * 256 + threadIdx.x;
  int n = t >> 3, g = t & 7;
  if (n >= NN) return;
  const u16* bp = yb + g * 8;
  float a0 = 0, a1 = 0, a2 = 0, a3 = 0, a4 = 0, a5 = 0, a6 = 0, a7 = 0;
  int rs = row[n], re = row[n + 1];
  int i = rs;
  for (; i + 8 <= re; i += 8) {
    uint4 v[8];
#pragma unroll
    for (int q = 0; q < 8; q++) {
      int s = csr[i + q];
      v[q] = *(const uint4*)(bp + (size_t)s * 64);
    }
#pragma unroll
    for (int q = 0; q < 8; q++) {
      a0 += bflo(v[q].x); a1 += bfhi(v[q].x); a2 += bflo(v[q].y); a3 += bfhi(v[q].y);
      a4 += bflo(v[q].z); a5 += bfhi(v[q].z); a6 += bflo(v[q].w); a7 += bfhi(v[q].w);
    }
  }
  for (; i + 4 <= re; i += 4) {
    uint4 v[4];
#pragma unroll
    for (int q = 0; q < 4; q++) {
      int s = csr[i + q];
      v[q] = *(const uint4*)(bp + (size_t)s * 64);
    }
#pragma unroll
    for (int q = 0; q < 4; q++) {
      a0 += bflo(v[q].x); a1 += bfhi(v[q].x); a2 += bflo(v[q].y); a3 += bfhi(v[q].y);
      a4 += bflo(v[q].z); a5 += bfhi(v[q].z); a6 += bflo(v[q].w); a7 += bfhi(v[q].w);
    }
  }
  for (; i < re; ++i) {
    int s = csr[i];
    uint4 v0 = *(const uint4*)(bp + (size_t)s * 64);
    a0 += bflo(v0.x); a1 += bfhi(v0.x); a2 += bflo(v0.y); a3 += bfhi(v0.y);
    a4 += bflo(v0.z); a5 += bfhi(v0.z); a6 += bflo(v0.w); a7 += bfhi(v0.w);
  }
  uint4 sv = *(const uint4*)(bp + (size_t)n * 64);
  float e1 = 1.0f + epsv[ei];
  const float* bb = b1 + g * 8;
  float r0 = fmaxf(fmaf(e1, bflo(sv.x), a0 + bb[0]), 0.f);
  float r1 = fmaxf(fmaf(e1, bfhi(sv.x), a1 + bb[1]), 0.f);
  float r2 = fmaxf(fmaf(e1, bflo(sv.y), a2 + bb[2]), 0.f);
  float r3 = fmaxf(fmaf(e1, bfhi(sv.y), a3 + bb[3]), 0.f);
  float r4 = fmaxf(fmaf(e1, bflo(sv.z), a4 + bb[4]), 0.f);
  float r5 = fmaxf(fmaf(e1, bfhi(sv.z), a5 + bb[5]), 0.f);
  float r6 = fmaxf(fmaf(e1, bflo(sv.w), a6 + bb[6]), 0.f);
  float r7 = fmaxf(fmaf(e1, bfhi(sv.w), a7 + bb[7]), 0.f);
  uint4 pk;
  pk.x = pkbf(r0, r1); pk.y = pkbf(r2, r3);
  pk.z = pkbf(r4, r5); pk.w = pkbf(r6, r7);
  *(uint4*)(ub + (size_t)n * 64 + g * 8) = pk;
}

// ---------------- MFMA MLP: yout = bf16( BN(relu(ub@w2+b2)) @ wn ) ----------------
__global__ void __launch_bounds__(256) k_mlp_mfma(
    const u16* __restrict__ ub, const float* __restrict__ w2, const float* __restrict__ b2,
    const float* __restrict__ gamma, const float* __restrict__ beta,
    const float* __restrict__ mean, const float* __restrict__ var,
    const float* __restrict__ wn, u16* __restrict__ yout) {
  __shared__ __align__(16) u16 w2T[64][72];
  __shared__ __align__(16) u16 wnT[64][72];
  __shared__ __align__(16) u16 ht[4][32][72];
  int tid = threadIdx.x;
  for (int idx = tid; idx < 4096; idx += 256) {
    int k = idx >> 6, n = idx & 63;
    w2T[n][k] = f2bf(w2[idx]);
    wnT[n][k] = f2bf(wn[idx]);
  }
  __syncthreads();
  int wid = tid >> 6, lane = tid & 63;
  int grp = blockIdx.x * 4 + wid;
  if (grp >= NN / 32) return;
  int g0 = grp * 32;
  int mrow = lane & 15;
  int kc8 = (lane >> 4) * 8;
  int q4 = (lane >> 4) * 4;
  float bb[4], gl[4], be[4], mn[4], rv[4];
#pragma unroll
  for (int nt = 0; nt < 4; nt++) {
    int j = nt * 16 + mrow;
    bb[nt] = b2[j]; gl[nt] = gamma[j]; be[nt] = beta[j]; mn[nt] = mean[j];
    rv[nt] = rsqrtf(var[j] + BN_EPS);
  }
  bf16x8 a[2][2];
#pragma unroll
  for (int mt = 0; mt < 2; mt++)
#pragma unroll
    for (int kc = 0; kc < 2; kc++)
      a[mt][kc] = frag_u16(ub + (size_t)(g0 + mt * 16 + mrow) * 64 + kc * 32 + kc8);
  f32x4 zero = {0.f, 0.f, 0.f, 0.f};
  f32x4 acc[2][4];
#pragma unroll
  for (int nt = 0; nt < 4; nt++) {
    bf16x8 b0 = frag_u16(&w2T[nt * 16 + mrow][kc8]);
    bf16x8 b1f = frag_u16(&w2T[nt * 16 + mrow][32 + kc8]);
#pragma unroll
    for (int mt = 0; mt < 2; mt++) {
      acc[mt][nt] = __builtin_amdgcn_mfma_f32_16x16x32_bf16(a[mt][0], b0, zero, 0, 0, 0);
      acc[mt][nt] = __builtin_amdgcn_mfma_f32_16x16x32_bf16(a[mt][1], b1f, acc[mt][nt], 0, 0, 0);
    }
  }
#pragma unroll
  for (int mt = 0; mt < 2; mt++)
#pragma unroll
    for (int nt = 0; nt < 4; nt++)
#pragma unroll
      for (int r = 0; r < 4; r++) {
        float v = fmaxf(acc[mt][nt][r] + bb[nt], 0.f);
        float h = fmaf(gl[nt] * (v - mn[nt]), rv[nt], be[nt]);
        ht[wid][mt * 16 + q4 + r][nt * 16 + mrow] = f2bf(h);
      }
  asm volatile("s_waitcnt lgkmcnt(0)" ::: "memory");
  bf16x8 a2[2][2];
#pragma unroll
  for (int mt = 0; mt < 2; mt++)
#pragma unroll
    for (int kc = 0; kc < 2; kc++)
      a2[mt][kc] = frag_u16(&ht[wid][mt * 16 + mrow][kc * 32 + kc8]);
  f32x4 ac2[2][4];
#pragma unroll
  for (int nt = 0; nt < 4; nt++) {
    bf16x8 b0 = frag_u16(&wnT[nt * 16 + mrow][kc8]);
    bf16x8 b1f = frag_u16(&wnT[nt * 16 + mrow][32 + kc8]);
#pragma unroll
    for (int mt = 0; mt < 2; mt++) {
      ac2[mt][nt] = __builtin_amdgcn_mfma_f32_16x16x32_bf16(a2[mt][0], b0, zero, 0, 0, 0);
      ac2[mt][nt] = __builtin_amdgcn_mfma_f32_16x16x32_bf16(a2[mt][1], b1f, ac2[mt][nt], 0, 0, 0);
    }
  }
  asm volatile("s_waitcnt lgkmcnt(0)" ::: "memory");
#pragma unroll
  for (int mt = 0; mt < 2; mt++)
#pragma unroll
    for (int nt = 0; nt < 4; nt++)
#pragma unroll
      for (int r = 0; r < 4; r++)
        ht[wid][mt * 16 + q4 + r][nt * 16 + mrow] = f2bf(ac2[mt][nt][r]);
  asm volatile("s_waitcnt lgkmcnt(0)" ::: "memory");
#pragma unroll
  for (int it = 0; it < 4; it++) {
    int idx = it * 64 + lane;
    int rw = idx >> 3, ch = idx & 7;
    uint4 v = *(const uint4*)&ht[wid][rw][ch * 8];
    *(uint4*)(yout + (size_t)(g0 + rw) * 64 + ch * 8) = v;
  }
}

// ---------------- MFMA final MLP + head ----------------
__global__ void __launch_bounds__(256) k_mlp_final_mfma(
    const u16* __restrict__ ub, const float* __restrict__ w2, const float* __restrict__ b2,
    const float* __restrict__ gamma, const float* __restrict__ beta,
    const float* __restrict__ mean, const float* __restrict__ var,
    const float* __restrict__ l1w, const float* __restrict__ l1b,
    const float* __restrict__ l2w, const float* __restrict__ l2b,
    float* __restrict__ out) {
  __shared__ __align__(16) u16 w2T[64][72];
  __shared__ __align__(16) u16 l1T[64][72];
  __shared__ __align__(16) u16 l2T[48][72];
  __shared__ __align__(16) u16 ht[4][32][72];
  int tid = threadIdx.x;
  for (int idx = tid; idx < 4096; idx += 256) {
    int k = idx >> 6, n = idx & 63;
    w2T[n][k] = f2bf(w2[idx]);
    l1T[n][k] = f2bf(l1w[idx]);
  }
  for (int idx = tid; idx < 3072; idx += 256) {
    int n = idx >> 6, k = idx & 63;
    l2T[n][k] = f2bf((n < 40) ? l2w[k * 40 + n] : 0.f);
  }
  __syncthreads();
  int wid = tid >> 6, lane = tid & 63;
  int grp = blockIdx.x * 4 + wid;
  if (grp >= NN / 32) return;
  int g0 = grp * 32;
  int mrow = lane & 15;
  int kc8 = (lane >> 4) * 8;
  int q4 = (lane >> 4) * 4;
  float bb[4], gl[4], be[4], mn[4], rv[4], l1bv[4];
#pragma unroll
  for (int nt = 0; nt < 4; nt++) {
    int j = nt * 16 + mrow;
    bb[nt] = b2[j]; gl[nt] = gamma[j]; be[nt] = beta[j]; mn[nt] = mean[j];
    rv[nt] = rsqrtf(var[j] + BN_EPS); l1bv[nt] = l1b[j];
  }
  float l2bv[3];
#pragma unroll
  for (int nt = 0; nt < 3; nt++) {
    int j = nt * 16 + mrow;
    l2bv[nt] = (j < 40) ? l2b[j] : 0.f;
  }
  bf16x8 a[2][2];
#pragma unroll
  for (int mt = 0; mt < 2; mt++)
#pragma unroll
    for (int kc = 0; kc < 2; kc++)
      a[mt][kc] = frag_u16(ub + (size_t)(g0 + mt * 16 + mrow) * 64 + kc * 32 + kc8);
  f32x4 zero = {0.f, 0.f, 0.f, 0.f};
  f32x4 acc[2][4];
#pragma unroll
  for (int nt = 0; nt < 4; nt++) {
    bf16x8 b0 = frag_u16(&w2T[nt * 16 + mrow][kc8]);
    bf16x8 b1f = frag_u16(&w2T[nt * 16 + mrow][32 + kc8]);
#pragma unroll
    for (int mt = 0; mt < 2; mt++) {
      acc[mt][nt] = __builtin_amdgcn_mfma_f32_16x16x32_bf16(a[mt][0], b0, zero, 0, 0, 0);
      acc[mt][nt] = __builtin_amdgcn_mfma_f32_16x16x32_bf16(a[mt][1], b1f, acc[mt][nt], 0, 0, 0);
    }
  }
#pragma unroll
  for (int mt = 0; mt < 2; mt++)
#pragma unroll
    for (int nt = 0; nt < 4; nt++)
#pragma unroll
      for (int r = 0; r < 4; r++) {
        float v = fmaxf(acc[mt][nt][r] + bb[nt], 0.f);
        float h = fmaf(gl[nt] * (v - mn[nt]), rv[nt], be[nt]);
        ht[wid][mt * 16 + q4 + r][nt * 16 + mrow] = f2bf(h);
      }
  asm volatile("s_waitcnt lgkmcnt(0)" ::: "memory");
  bf16x8 a2[2][2];
#pragma unroll
  for (int mt = 0; mt < 2; mt++)
#pragma unroll
    for (int kc = 0; kc < 2; kc++)
      a2[mt][kc] = frag_u16(&ht[wid][mt * 16 + mrow][kc * 32 + kc8]);
  f32x4 ac2[2][4];
#pragma unroll
  for (int nt = 0; nt < 4; nt++) {
    bf16x8 b0 = frag_u16(&l1T[nt * 16 + mrow][kc8]);
    bf16x8 b1f = frag_u16(&l1T[nt * 16 + mrow][32 + kc8]);
#pragma unroll
    for (int mt = 0; mt < 2; mt++) {
      ac2[mt][nt] = __builtin_amdgcn_mfma_f32_16x16x32_bf16(a2[mt][0], b0, zero, 0, 0, 0);
      ac2[mt][nt] = __builtin_amdgcn_mfma_f32_16x16x32_bf16(a2[mt][1], b1f, ac2[mt][nt], 0, 0, 0);
    }
  }
  asm volatile("s_waitcnt lgkmcnt(0)" ::: "memory");
#pragma unroll
  for (int mt = 0; mt < 2; mt++)
#pragma unroll
    for (int nt = 0; nt < 4; nt++)
#pragma unroll
      for (int r = 0; r < 4; r++) {
        float f = fmaxf(ac2[mt][nt][r] + l1bv[nt], 0.f);
        ht[wid][mt * 16 + q4 + r][nt * 16 + mrow] = f2bf(f);
      }
  asm volatile("s_waitcnt lgkmcnt(0)" ::: "memory");
  bf16x8 a3[2][2];
#pragma unroll
  for (int mt = 0; mt < 2; mt++)
#pragma unroll
    for (int kc = 0; kc < 2; kc++)
      a3[mt][kc] = frag_u16(&ht[wid][mt * 16 + mrow][kc * 32 + kc8]);
  f32x4 ac3[2][3];
#pragma unroll
  for (int nt = 0; nt < 3; nt++) {
    bf16x8 b0 = frag_u16(&l2T[nt * 16 + mrow][kc8]);
    bf16x8 b1f = frag_u16(&l2T[nt * 16 + mrow][32 + kc8]);
#pragma unroll
    for (int mt = 0; mt < 2; mt++) {
      ac3[mt][nt] = __builtin_amdgcn_mfma_f32_16x16x32_bf16(a3[mt][0], b0, zero, 0, 0, 0);
      ac3[mt][nt] = __builtin_amdgcn_mfma_f32_16x16x32_bf16(a3[mt][1], b1f, ac3[mt][nt], 0, 0, 0);
    }
  }
#pragma unroll
  for (int mt = 0; mt < 2; mt++)
#pragma unroll
    for (int nt = 0; nt < 3; nt++) {
      int j = nt * 16 + mrow;
      if (j < 40) {
#pragma unroll
        for (int r = 0; r < 4; r++)
          out[(size_t)(g0 + mt * 16 + q4 + r) * 40 + j] = ac3[mt][nt][r] + l2bv[nt];
      }
    }
}

extern "C" void kernel_launch(void* const* d_in, const int* in_sizes, int n_in,
                              void* d_out, int out_size, void* d_ws, size_t ws_size,
                              hipStream_t stream) {
  const float* x   = (const float*)d_in[0];
  const int*   ei  = (const int*)d_in[1];
  const int*   src = ei;
  const int*   dst = ei + NE;
  const float* eps = (const float*)d_in[2];
  const float* c1_w1 = (const float*)d_in[3];
  const float* c1_b1 = (const float*)d_in[4];
  const float* c1_w2 = (const float*)d_in[5];
  const float* c1_b2 = (const float*)d_in[6];
  const float* c1_gamma = (const float*)d_in[7];
  const float* c1_beta  = (const float*)d_in[8];
  const float* c1_mean  = (const float*)d_in[9];
  const float* c1_var   = (const float*)d_in[10];
  const float* cw1 = (const float*)d_in[11];
  const float* cb1 = (const float*)d_in[12];
  const float* cw2 = (const float*)d_in[13];
  const float* cb2 = (const float*)d_in[14];
  const float* cgamma = (const float*)d_in[15];
  const float* cbeta  = (const float*)d_in[16];
  const float* cmean  = (const float*)d_in[17];
  const float* cvar   = (const float*)d_in[18];
  const float* lin1_w = (const float*)d_in[19];
  const float* lin1_b = (const float*)d_in[20];
  const float* lin2_w = (const float*)d_in[21];
  const float* lin2_b = (const float*)d_in[22];
  float* out = (float*)d_out;

  char* ws = (char*)d_ws;
  int* row  = (int*)(ws + OFF_ROW);
  int* ctrl = (int*)(ws + OFF_CTRL);
  int* ch   = ctrl;
  int* coff = ctrl + 128;
  int* ccur = ctrl + 256;
  int* csr  = (int*)(ws + OFF_CSR);
  u32* pairs1 = (u32*)(ws + OFF_P1);
  u16* ubuf = (u16*)(ws + OFF_U);
  u16* yb0  = (u16*)(ws + OFF_YB0);
  u16* yb1  = (u16*)(ws + OFF_YB1);

  hipMemsetAsync(ch, 0, NCOARSE * 4, stream);

  k_hist_c<<<512, 256, 0, stream>>>(dst, ch);
  k_scan_c<<<1, 64, 0, stream>>>(ch, coff, ccur);
  k_scat1<<<(NE + SC_CH - 1) / SC_CH, 256, 0, stream>>>(src, dst, ccur, pairs1);
  k_fill3<<<NCOARSE, 256, 0, stream>>>(pairs1, coff, row, csr);

  const int AGG_GRID = (NN * 8) / 256;          // 3125
  const int MLP_GRID = (NN / 32 + 3) / 4;       // 782

  // y0 = bf16(x @ c1_w1), MFMA
  k_gemm_x_mfma<<<MLP_GRID, 256, 0, stream>>>(x, c1_w1, yb0);

  // layer 1
  k_agg<<<AGG_GRID, 256, 0, stream>>>(yb0, row, csr, eps, 0, c1_b1, ubuf);
  k_mlp_mfma<<<MLP_GRID, 256, 0, stream>>>(ubuf, c1_w2, c1_b2,
                                           c1_gamma, c1_beta, c1_mean, c1_var,
                                           cw1, yb1);
  // layer 2
  k_agg<<<AGG_GRID, 256, 0, stream>>>(yb1, row, csr, eps, 1, cb1, ubuf);
  k_mlp_mfma<<<MLP_GRID, 256, 0, stream>>>(ubuf, cw2, cb2,
                                           cgamma, cbeta, cmean, cvar,
                                           cw1 + 64 * 64, yb0);
  // layer 3 + head
  k_agg<<<AGG_GRID, 256, 0, stream>>>(yb0, row, csr, eps, 2, cb1 + 64, ubuf);
  k_mlp_final_mfma<<<MLP_GRID, 256, 0, stream>>>(ubuf, cw2 + 64 * 64, cb2 + 64,
                                                 cgamma + 64, cbeta + 64, cmean + 64, cvar + 64,
                                                 lin1_w, lin1_b, lin2_w, lin2_b,
                                                 out);
}